// Round 5
// baseline (358.543 us; speedup 1.0000x reference)
//
#include <hip/hip_runtime.h>

typedef unsigned short u16;
typedef unsigned int u32;
typedef __attribute__((ext_vector_type(8))) short short8;
typedef __attribute__((ext_vector_type(4))) float float4v;

#define N_NODES 100000
#define N_EDGES 1600000
#define N_PAIRS 100000
#define NBUCKP 256
#define NB_USED 196
#define BUCK_CAP 8704
#define BIN_GRID 391

__device__ __forceinline__ float bf2f(u32 lo16) {
    union { u32 u; float f; } v;
    v.u = lo16 << 16;
    return v.f;
}
__device__ __forceinline__ u16 f2bf(float f) {
    union { float f; u32 u; } v;
    v.f = f;
    u32 r = v.u + 0x7fffu + ((v.u >> 16) & 1u);
    return (u16)(r >> 16);
}

// f16-pair decode + mixed-precision MAC:
//  Q = v_perm packed (0x6400|u1,0x6400|u0) = f16 values (1152+q1, 1152+q0), exact.
//  v_fma_mix_f32: acc(f32) += f16(Q half) * f16(W lo). Offset removed via swl.
#define FMIX_LO(A, Q, W) asm("v_fma_mix_f32 %0, %1, %2, %0 op_sel:[0,0,0] op_sel_hi:[1,1,0]" : "+v"(A) : "v"(Q), "v"(W))
#define FMIX_HI(A, Q, W) asm("v_fma_mix_f32 %0, %1, %2, %0 op_sel:[1,0,0] op_sel_hi:[1,1,0]" : "+v"(A) : "v"(Q), "v"(W))

// ---------------- pre-swizzle weights + init bucket cursors (block 32) ----------------
__global__ __launch_bounds__(256) void k_prepB4(const float* __restrict__ W1, const float* __restrict__ W2,
                                                const float* __restrict__ WA, const float* __restrict__ WB,
                                                u16* __restrict__ B1, u16* __restrict__ B2,
                                                u16* __restrict__ BA, u16* __restrict__ BB,
                                                int* __restrict__ bucket_cur) {
    if (blockIdx.x == 32) {
        bucket_cur[threadIdx.x] = threadIdx.x * BUCK_CAP;
        return;
    }
    int w = blockIdx.x >> 3;
    const float* W = (w == 0) ? W1 : (w == 1) ? W2 : (w == 2) ? WA : WB;
    u16* Bf = (w == 0) ? B1 : (w == 1) ? B2 : (w == 2) ? BA : BB;
    int t = (blockIdx.x & 7) * 256 + threadIdx.x;
    int kk = t >> 9, tn = (t >> 6) & 7, quad = (t >> 4) & 3, l15 = t & 15;
#pragma unroll
    for (int j = 0; j < 8; j++) {
        int k = kk * 32 + quad * 8 + j;
        int n = tn * 16 + l15;
        Bf[(size_t)t * 8 + j] = f2bf(W[k * 128 + n]);
    }
}

// ---------------- bin edges into padded buckets ----------------
__global__ __launch_bounds__(256) void k_bin(const int* __restrict__ esrc, const int* __restrict__ edst,
                                             int* bucket_cur, int2* __restrict__ binned) {
    __shared__ int cnt[NBUCKP];
    __shared__ int base[NBUCKP];
    int t = threadIdx.x;
    cnt[t] = 0;
    __syncthreads();
    int s[16], d[16], r[16];
    int e0 = blockIdx.x * 4096;
#pragma unroll
    for (int k = 0; k < 16; k++) {
        int e = e0 + k * 256 + t;
        if (e < N_EDGES) {
            s[k] = esrc[e];
            d[k] = edst[e];
            r[k] = atomicAdd(&cnt[d[k] >> 9], 1);
        } else {
            d[k] = -1;
        }
    }
    __syncthreads();
    base[t] = cnt[t] ? atomicAdd(&bucket_cur[t], cnt[t]) : 0;
    __syncthreads();
#pragma unroll
    for (int k = 0; k < 16; k++) {
        if (d[k] >= 0) {
            int bk = d[k] >> 9;
            int pos = base[bk] + r[k];
            if (pos < (bk + 1) * BUCK_CAP)
                binned[pos] = make_int2(s[k], d[k]);
        }
    }
}

// ---------------- per-bucket LDS counting sort -> row_ptr + col_src ----------------
__global__ __launch_bounds__(512) void k_sort(const int2* __restrict__ binned,
                                              const int* __restrict__ bucket_cur,
                                              int* __restrict__ row_ptr,
                                              int* __restrict__ col_src) {
    __shared__ int cnt[512];
    __shared__ int sm[512];
    int b = blockIdx.x, t = threadIdx.x;

    int partial = 0;
    if (t < b) partial = bucket_cur[t] - t * BUCK_CAP;
    sm[t] = partial;
    __syncthreads();
    for (int o = 256; o >= 1; o >>= 1) {
        if (t < o) sm[t] += sm[t + o];
        __syncthreads();
    }
    int base = sm[0];
    int n_e = bucket_cur[b] - b * BUCK_CAP;
    if (n_e > BUCK_CAP) n_e = BUCK_CAP;
    __syncthreads();

    cnt[t] = 0;
    __syncthreads();
    const int2* ebase = binned + (size_t)b * BUCK_CAP;
    for (int i = t; i < n_e; i += 512)
        atomicAdd(&cnt[ebase[i].y & 511], 1);
    __syncthreads();
    int v = cnt[t];
    sm[t] = v;
    __syncthreads();
    for (int o = 1; o < 512; o <<= 1) {
        int x = (t >= o) ? sm[t - o] : 0;
        __syncthreads();
        sm[t] += x;
        __syncthreads();
    }
    int excl = base + sm[t] - v;
    int node = b * 512 + t;
    if (node <= N_NODES) row_ptr[node] = excl;
    cnt[t] = excl;
    __syncthreads();
    for (int i = t; i < n_e; i += 512) {
        int2 sd = ebase[i];
        int p = atomicAdd(&cnt[sd.y & 511], 1);
        col_src[p] = sd.x;
    }
}

// ---------------- MFMA GEMM ----------------
// QUANT: biased-u8 row-quantized hq (u = q+128) + alsc[row] interleaved pairs
// {al_s[h], scale} x4 + al_d.
template<bool AF32, bool DUAL, bool QUANT>
__global__ __launch_bounds__(256) void k_gemm(const void* __restrict__ Ap,
                                              const u16* __restrict__ Bf,
                                              const u16* __restrict__ Bf2,
                                              u16* __restrict__ C,
                                              u16* __restrict__ C2,
                                              char* __restrict__ hq,
                                              float* __restrict__ alsc,
                                              const float* __restrict__ a_src,
                                              const float* __restrict__ a_dst,
                                              float* __restrict__ al_d, int M) {
    int wave = threadIdx.x >> 6, lane = threadIdx.x & 63;
    int quad = lane >> 4, l15 = lane & 15;
    int row0 = blockIdx.x * 64 + wave * 16;
    int m = row0 + l15;
    int mload = (m < M) ? m : (M - 1);

    short8 a[4];
    if (AF32) {
        const float* A = (const float*)Ap;
#pragma unroll
        for (int kk = 0; kk < 4; kk++) {
            const float* p = A + (size_t)mload * 128 + kk * 32 + quad * 8;
            float4 f0 = *(const float4*)p;
            float4 f1 = *(const float4*)(p + 4);
            short8 av;
            av[0] = (short)f2bf(f0.x); av[1] = (short)f2bf(f0.y);
            av[2] = (short)f2bf(f0.z); av[3] = (short)f2bf(f0.w);
            av[4] = (short)f2bf(f1.x); av[5] = (short)f2bf(f1.y);
            av[6] = (short)f2bf(f1.z); av[7] = (short)f2bf(f1.w);
            a[kk] = av;
        }
    } else {
        const u16* A = (const u16*)Ap;
#pragma unroll
        for (int kk = 0; kk < 4; kk++)
            a[kk] = *(const short8*)(A + (size_t)mload * 128 + kk * 32 + quad * 8);
    }

    float4v acc[8], acc2[8];
#pragma unroll
    for (int tn = 0; tn < 8; tn++) {
        acc[tn] = (float4v){0.f, 0.f, 0.f, 0.f};
        if (DUAL) acc2[tn] = (float4v){0.f, 0.f, 0.f, 0.f};
    }

#pragma unroll
    for (int kk = 0; kk < 4; kk++) {
#pragma unroll
        for (int tn = 0; tn < 8; tn++) {
            short8 b = *(const short8*)(Bf + ((size_t)((kk * 8 + tn) * 64 + lane)) * 8);
            acc[tn] = __builtin_amdgcn_mfma_f32_16x16x32_bf16(a[kk], b, acc[tn], 0, 0, 0);
            if (DUAL) {
                short8 b2 = *(const short8*)(Bf2 + ((size_t)((kk * 8 + tn) * 64 + lane)) * 8);
                acc2[tn] = __builtin_amdgcn_mfma_f32_16x16x32_bf16(a[kk], b2, acc2[tn], 0, 0, 0);
            }
        }
    }

    float as0[4], as1[4], ad0[4], ad1[4];
    if (QUANT) {
#pragma unroll
        for (int hd = 0; hd < 4; hd++) {
            as0[hd] = a_src[hd * 32 + l15];
            as1[hd] = a_src[hd * 32 + 16 + l15];
            ad0[hd] = a_dst[hd * 32 + l15];
            ad1[hd] = a_dst[hd * 32 + 16 + l15];
        }
    }

#pragma unroll
    for (int rg = 0; rg < 4; rg++) {
        int gr = row0 + quad * 4 + rg;
        bool ok = (gr < M);
        if (!QUANT) {
            if (ok) {
#pragma unroll
                for (int tn = 0; tn < 8; tn++) {
                    C[(size_t)gr * 128 + tn * 16 + l15] = f2bf(acc[tn][rg]);
                    if (DUAL) C2[(size_t)gr * 128 + tn * 16 + l15] = f2bf(acc2[tn][rg]);
                }
            }
        } else {
            float amax = 0.f;
#pragma unroll
            for (int tn = 0; tn < 8; tn++) amax = fmaxf(amax, fabsf(acc[tn][rg]));
#pragma unroll
            for (int mm = 1; mm < 16; mm <<= 1) amax = fmaxf(amax, __shfl_xor(amax, mm, 64));
            float inv_s = (amax > 0.f) ? 127.f / amax : 0.f;
            if (ok) {
#pragma unroll
                for (int tn = 0; tn < 8; tn++) {
                    int q = (int)rintf(acc[tn][rg] * inv_s);
                    hq[(size_t)gr * 128 + tn * 16 + l15] = (char)(q + 128);   // biased u8
                }
            }
            float ps[4], pd[4];
#pragma unroll
            for (int hd = 0; hd < 4; hd++) {
                float c0 = acc[2 * hd][rg];
                float c1 = acc[2 * hd + 1][rg];
                ps[hd] = c0 * as0[hd] + c1 * as1[hd];
                pd[hd] = c0 * ad0[hd] + c1 * ad1[hd];
            }
#pragma unroll
            for (int mm = 1; mm < 16; mm <<= 1) {
#pragma unroll
                for (int hd = 0; hd < 4; hd++) {
                    ps[hd] += __shfl_xor(ps[hd], mm, 64);
                    pd[hd] += __shfl_xor(pd[hd], mm, 64);
                }
            }
            if (ok && l15 < 4) {
                float vs = (l15 == 0) ? ps[0] : (l15 == 1) ? ps[1] : (l15 == 2) ? ps[2] : ps[3];
                float vd = (l15 == 0) ? pd[0] : (l15 == 1) ? pd[1] : (l15 == 2) ? pd[2] : pd[3];
                alsc[(size_t)gr * 8 + l15 * 2]     = vs;                       // al_s[h]
                alsc[(size_t)gr * 8 + l15 * 2 + 1] = amax * (1.f / 127.f);     // scale (paired)
                al_d[gr * 4 + l15] = vd;
            }
        }
    }
}

// ---------------- fused aggregation: flat 32-edge body, 32 rows in flight ----------------
// deg<=32 (P[deg>32] ~ 1e-5 for Poisson(16)): single branch-free body.
//  - 10 tiny col_src loads (L1) issue right after row_ptr: no shfl on address path.
//  - ALL 8 row gathers (4 rows per dwordx2 instr = 32 rows) issue before any decode.
//  - phase A (lane = slot*4+head, 2 rounds): w = exp(leaky(al_s+al_d)) once per
//    (edge,head); pads -> w=0; clamped indices make pad gathers L1 hits.
//  - decode: v_perm (biased u8 -> packed f16 = 1152+q, exact) + v_fma_mix_f32.
// deg>32 tail: uniform readfirstlane loop, grp0-predicated (exact, ~1e-5 of nodes).
template<bool XF32>
__global__ __launch_bounds__(256) void k_agg(const int* __restrict__ row_ptr, const int* __restrict__ col_src,
                      const float* __restrict__ alsc, const float* __restrict__ al_d,
                      const char* __restrict__ hq,
                      const void* __restrict__ xin, u16* __restrict__ xout) {
    int node = blockIdx.x * 4 + (threadIdx.x >> 6);
    int lane = threadIdx.x & 63;
    int l15 = lane & 15;
    int grp = lane >> 4;          // phase-B edge subgroup (0..3)
    int bh  = l15 >> 2;           // head of this lane's 8 dims
    int ae  = lane >> 2;          // phase-A edge slot (0..15)
    int ah  = lane & 3;           // phase-A head
    int beg = row_ptr[node], end = row_ptr[node + 1];
    int deg = end - beg;
    u32 loff = (u32)(l15 * 8);    // byte offset within a row

    // residual (independent, issue early)
    float r[8];
    if (XF32) {
        const float* x = (const float*)xin;
        float4 x0 = *(const float4*)&x[(size_t)node * 128 + l15 * 8];
        float4 x1 = *(const float4*)&x[(size_t)node * 128 + l15 * 8 + 4];
        r[0] = x0.x; r[1] = x0.y; r[2] = x0.z; r[3] = x0.w;
        r[4] = x1.x; r[5] = x1.y; r[6] = x1.z; r[7] = x1.w;
    } else {
        const u16* x = (const u16*)xin;
        short8 xv = *(const short8*)&x[(size_t)node * 128 + l15 * 8];
#pragma unroll
        for (int k = 0; k < 8; k++) r[k] = bf2f((u16)xv[k]);
    }

    if (deg == 0) {               // wave-uniform; avoids col_src[beg] OOB deref
        if (grp == 0) {
            u32 ow[4];
#pragma unroll
            for (int k = 0; k < 4; k++)
                ow[k] = (u32)f2bf(r[2 * k]) | ((u32)f2bf(r[2 * k + 1]) << 16);
            *(uint4*)&xout[(size_t)node * 128 + l15 * 8] = make_uint4(ow[0], ow[1], ow[2], ow[3]);
        }
        return;
    }
    int degm1 = deg - 1;
    float adst = al_d[node * 4 + ah];

    // ---- index loads: all tiny, all independent, all L1-resident
    int slotA0 = (ae <= degm1) ? ae : degm1;
    int slotA1 = (ae + 16 <= degm1) ? ae + 16 : degm1;
    int sA0 = col_src[beg + slotA0];
    int sA1 = col_src[beg + slotA1];
    int sB[8];
#pragma unroll
    for (int i = 0; i < 8; i++) {
        int slot = i * 4 + grp;
        slot = (slot <= degm1) ? slot : degm1;
        sB[i] = col_src[beg + slot];
    }

    // ---- phase-A alpha loads + ALL 8 row gathers (32 rows in flight)
    float2 avA0 = *(const float2*)(alsc + ((size_t)sA0 << 3) + (ah << 1));
    float2 avA1 = *(const float2*)(alsc + ((size_t)sA1 << 3) + (ah << 1));
    uint2 hv[8];
#pragma unroll
    for (int i = 0; i < 8; i++)
        hv[i] = *(const uint2*)(hq + (((u32)sB[i]) << 7) + loff);

    // ---- phase A: weights for 32 (edge,head) pairs
    float ev0 = avA0.x + adst;
    ev0 = fmaxf(ev0, 0.2f * ev0);
    float w0 = __expf(ev0);
    w0 = (ae < deg) ? w0 : 0.f;
    float ev1 = avA1.x + adst;
    ev1 = fmaxf(ev1, 0.2f * ev1);
    float w1 = __expf(ev1);
    w1 = (ae + 16 < deg) ? w1 : 0.f;
    float sw = w0 + w1;
    float wsc0 = w0 * avA0.y;
    float wsc1 = w1 * avA1.y;

    // sum(w): reduce over slot bits 2..5 (head preserved in bits 0..1)
#pragma unroll
    for (int mm = 4; mm < 64; mm <<= 1) sw += __shfl_xor(sw, mm, 64);

    // ---- decode: 8 iterations x 4 edges
    float swl = 0.f;
    u32 h_one = 0x3C00u;          // f16 1.0
    float acc[8];
#pragma unroll
    for (int k = 0; k < 8; k++) acc[k] = 0.f;

#pragma unroll
    for (int i = 0; i < 8; i++) {
        int slot = i * 4 + grp;   // 0..31, always a valid weight slot (pads have w=0)
        float wl = (i < 4) ? __shfl(wsc0, slot * 4 + bh, 64)
                           : __shfl(wsc1, (slot - 16) * 4 + bh, 64);
        u32 wlh;
        asm("v_cvt_f16_f32 %0, %1" : "=v"(wlh) : "v"(wl));
        FMIX_LO(swl, h_one, wlh);
        u32 p01 = __builtin_amdgcn_perm(0x64646464u, hv[i].x, 0x04010400u);
        u32 p23 = __builtin_amdgcn_perm(0x64646464u, hv[i].x, 0x04030402u);
        u32 p45 = __builtin_amdgcn_perm(0x64646464u, hv[i].y, 0x04010400u);
        u32 p67 = __builtin_amdgcn_perm(0x64646464u, hv[i].y, 0x04030402u);
        FMIX_LO(acc[0], p01, wlh); FMIX_HI(acc[1], p01, wlh);
        FMIX_LO(acc[2], p23, wlh); FMIX_HI(acc[3], p23, wlh);
        FMIX_LO(acc[4], p45, wlh); FMIX_HI(acc[5], p45, wlh);
        FMIX_LO(acc[6], p67, wlh); FMIX_HI(acc[7], p67, wlh);
    }

    // ---- rare tail: deg > 32 (wave-uniform)
    float swt = 0.f;
    if (deg > 32) {
        float adstB = al_d[node * 4 + bh];
        for (int i = 32; i < deg; i++) {
            int s = __builtin_amdgcn_readfirstlane(col_src[beg + i]);
            float2 av = *(const float2*)(alsc + ((size_t)s << 3) + (bh << 1));
            float ev = av.x + adstB;
            ev = fmaxf(ev, 0.2f * ev);
            float w = __expf(ev);
            swt += w;                                  // identical across lanes of a head
            float wl = (grp == 0) ? w * av.y : 0.f;    // contribute once (pre-reduction)
            u32 wlh;
            asm("v_cvt_f16_f32 %0, %1" : "=v"(wlh) : "v"(wl));
            FMIX_LO(swl, h_one, wlh);
            uint2 hvt = *(const uint2*)(hq + (((u32)s) << 7) + loff);
            u32 p01 = __builtin_amdgcn_perm(0x64646464u, hvt.x, 0x04010400u);
            u32 p23 = __builtin_amdgcn_perm(0x64646464u, hvt.x, 0x04030402u);
            u32 p45 = __builtin_amdgcn_perm(0x64646464u, hvt.y, 0x04010400u);
            u32 p67 = __builtin_amdgcn_perm(0x64646464u, hvt.y, 0x04030402u);
            FMIX_LO(acc[0], p01, wlh); FMIX_HI(acc[1], p01, wlh);
            FMIX_LO(acc[2], p23, wlh); FMIX_HI(acc[3], p23, wlh);
            FMIX_LO(acc[4], p45, wlh); FMIX_HI(acc[5], p45, wlh);
            FMIX_LO(acc[6], p67, wlh); FMIX_HI(acc[7], p67, wlh);
        }
    }

    // remove the +1152 bias: acc_true = acc - 1152 * sum(wl)
#pragma unroll
    for (int k = 0; k < 8; k++) acc[k] = fmaf(swl, -1152.f, acc[k]);

    float inv = 1.f / (__shfl(sw, bh, 64) + swt + 1e-10f);

    // reduce accumulators across the 4 edge-subgroups (lane bits 4,5)
#pragma unroll
    for (int k = 0; k < 8; k++) {
        acc[k] += __shfl_xor(acc[k], 16, 64);
        acc[k] += __shfl_xor(acc[k], 32, 64);
    }

    if (grp == 0) {
        u32 ow[4];
#pragma unroll
        for (int k = 0; k < 4; k++) {
            float a0 = acc[2 * k] * inv;
            float a1 = acc[2 * k + 1] * inv;
            a0 = (a0 > 0.f) ? a0 : (__expf(a0) - 1.f);
            a1 = (a1 > 0.f) ? a1 : (__expf(a1) - 1.f);
            ow[k] = (u32)f2bf(a0 + r[2 * k]) | ((u32)f2bf(a1 + r[2 * k + 1]) << 16);
        }
        *(uint4*)&xout[(size_t)node * 128 + l15 * 8] = make_uint4(ow[0], ow[1], ow[2], ow[3]);
    }
}

// ---------------- link predictor ----------------
__global__ void k_pair(const int* __restrict__ psrc, const int* __restrict__ pdst,
                       const u16* __restrict__ u, const u16* __restrict__ v,
                       const float* __restrict__ b1, const float* __restrict__ w2,
                       const float* __restrict__ b2, float* __restrict__ out) {
    int p = blockIdx.x * 4 + (threadIdx.x >> 6);
    int lane = threadIdx.x & 63;
    int s = psrc[p], d = pdst[p];
    float h0 = bf2f(u[(size_t)s * 128 + lane * 2])     + bf2f(v[(size_t)d * 128 + lane * 2])     + b1[lane * 2];
    float h1 = bf2f(u[(size_t)s * 128 + lane * 2 + 1]) + bf2f(v[(size_t)d * 128 + lane * 2 + 1]) + b1[lane * 2 + 1];
    h0 = (h0 > 0.f) ? h0 : 0.f;
    h1 = (h1 > 0.f) ? h1 : 0.f;
    float acc = h0 * w2[lane * 2] + h1 * w2[lane * 2 + 1];
#pragma unroll
    for (int m = 1; m < 64; m <<= 1) acc += __shfl_xor(acc, m, 64);
    if (lane == 0) out[p] = acc + b2[0];
}

extern "C" void kernel_launch(void* const* d_in, const int* in_sizes, int n_in,
                              void* d_out, int out_size, void* d_ws, size_t ws_size,
                              hipStream_t stream) {
    const float* embed  = (const float*)d_in[0];
    const float* W1     = (const float*)d_in[1];
    const float* a_src1 = (const float*)d_in[2];
    const float* a_dst1 = (const float*)d_in[3];
    const float* W2     = (const float*)d_in[4];
    const float* a_src2 = (const float*)d_in[5];
    const float* a_dst2 = (const float*)d_in[6];
    const float* lp_w1  = (const float*)d_in[7];
    const float* lp_b1  = (const float*)d_in[8];
    const float* lp_w2  = (const float*)d_in[9];
    const float* lp_b2  = (const float*)d_in[10];
    const int*   edge   = (const int*)d_in[11];
    const int*   lsrc   = (const int*)d_in[12];
    const int*   ldst   = (const int*)d_in[13];
    float* out = (float*)d_out;

    char* ws = (char*)d_ws;
    size_t off = 0;
    auto alloc = [&](size_t bytes) -> char* {
        char* p = ws + off;
        off += (bytes + 255) & ~(size_t)255;
        return p;
    };
    int*  row_ptr    = (int*)alloc((N_NODES + 1) * 4);
    int*  bucket_cur = (int*)alloc(NBUCKP * 4);
    int2* binned     = (int2*)alloc((size_t)NBUCKP * BUCK_CAP * 8);
    int*  col_src    = (int*)alloc((size_t)N_EDGES * 4);
    char* hq         = (char*)alloc((size_t)N_NODES * 128);
    float* alsc      = (float*)alloc((size_t)N_NODES * 8 * 4);
    float* al_d      = (float*)alloc((size_t)N_NODES * 4 * 4);
    u16*  x1         = (u16*)alloc((size_t)N_NODES * 128 * 2);
    u16*  z          = (u16*)alloc((size_t)N_NODES * 128 * 2);
    u16*  uu         = (u16*)alloc((size_t)N_NODES * 128 * 2);
    u16*  vv         = (u16*)alloc((size_t)N_NODES * 128 * 2);
    u16*  Bf1        = (u16*)alloc(128 * 128 * 2);
    u16*  Bf2        = (u16*)alloc(128 * 128 * 2);
    u16*  BfA        = (u16*)alloc(128 * 128 * 2);
    u16*  BfB        = (u16*)alloc(128 * 128 * 2);

    const int* esrc = edge;
    const int* edst = edge + N_EDGES;
    const int GB = (N_NODES + 63) / 64;

    k_prepB4<<<33, 256, 0, stream>>>(W1, W2, lp_w1, lp_w1 + 128 * 128, Bf1, Bf2, BfA, BfB, bucket_cur);

    k_bin <<<BIN_GRID, 256, 0, stream>>>(esrc, edst, bucket_cur, binned);
    k_sort<<<NB_USED, 512, 0, stream>>>(binned, bucket_cur, row_ptr, col_src);

    // layer 1: hq = u8(embed @ W1), fused alpha+scale pack
    k_gemm<true, false, true><<<GB, 256, 0, stream>>>(embed, Bf1, nullptr, nullptr, nullptr,
                                                      hq, alsc, a_src1, a_dst1, al_d, N_NODES);
    k_agg<true><<<N_NODES / 4, 256, 0, stream>>>(row_ptr, col_src, alsc, al_d, hq, embed, x1);
    // layer 2
    k_gemm<false, false, true><<<GB, 256, 0, stream>>>(x1, Bf2, nullptr, nullptr, nullptr,
                                                       hq, alsc, a_src2, a_dst2, al_d, N_NODES);
    k_agg<false><<<N_NODES / 4, 256, 0, stream>>>(row_ptr, col_src, alsc, al_d, hq, x1, z);
    // link predictor
    k_gemm<false, true, false><<<GB, 256, 0, stream>>>(z, BfA, BfB, uu, vv,
                                                       nullptr, nullptr, nullptr, nullptr, nullptr, N_NODES);
    k_pair<<<N_PAIRS / 4, 256, 0, stream>>>(lsrc, ldst, uu, vv, lp_b1, lp_w2, lp_b2, out);
}

// Round 6
// 328.686 us; speedup vs baseline: 1.0908x; 1.0908x over previous
//
#include <hip/hip_runtime.h>

typedef unsigned short u16;
typedef unsigned int u32;
typedef __attribute__((ext_vector_type(8))) short short8;
typedef __attribute__((ext_vector_type(4))) float float4v;

#define N_NODES 100000
#define N_EDGES 1600000
#define N_PAIRS 100000
#define NBUCKP 256
#define NB_USED 196
#define BUCK_CAP 8704
#define BIN_GRID 391

__device__ __forceinline__ float bf2f(u32 lo16) {
    union { u32 u; float f; } v;
    v.u = lo16 << 16;
    return v.f;
}
__device__ __forceinline__ u16 f2bf(float f) {
    union { float f; u32 u; } v;
    v.f = f;
    u32 r = v.u + 0x7fffu + ((v.u >> 16) & 1u);
    return (u16)(r >> 16);
}

// f16-pair decode + mixed-precision MAC:
//  Q = v_perm packed (0x6400|u1,0x6400|u0) = f16 values (1152+q1, 1152+q0), exact.
//  v_fma_mix_f32: acc(f32) += f16(Q half) * f16(W lo). Offset removed via swl.
#define FMIX_LO(A, Q, W) asm("v_fma_mix_f32 %0, %1, %2, %0 op_sel:[0,0,0] op_sel_hi:[1,1,0]" : "+v"(A) : "v"(Q), "v"(W))
#define FMIX_HI(A, Q, W) asm("v_fma_mix_f32 %0, %1, %2, %0 op_sel:[1,0,0] op_sel_hi:[1,1,0]" : "+v"(A) : "v"(Q), "v"(W))

// ---------------- pre-swizzle weights + init bucket cursors (block 32) ----------------
__global__ __launch_bounds__(256) void k_prepB4(const float* __restrict__ W1, const float* __restrict__ W2,
                                                const float* __restrict__ WA, const float* __restrict__ WB,
                                                u16* __restrict__ B1, u16* __restrict__ B2,
                                                u16* __restrict__ BA, u16* __restrict__ BB,
                                                int* __restrict__ bucket_cur) {
    if (blockIdx.x == 32) {
        bucket_cur[threadIdx.x] = threadIdx.x * BUCK_CAP;
        return;
    }
    int w = blockIdx.x >> 3;
    const float* W = (w == 0) ? W1 : (w == 1) ? W2 : (w == 2) ? WA : WB;
    u16* Bf = (w == 0) ? B1 : (w == 1) ? B2 : (w == 2) ? BA : BB;
    int t = (blockIdx.x & 7) * 256 + threadIdx.x;
    int kk = t >> 9, tn = (t >> 6) & 7, quad = (t >> 4) & 3, l15 = t & 15;
#pragma unroll
    for (int j = 0; j < 8; j++) {
        int k = kk * 32 + quad * 8 + j;
        int n = tn * 16 + l15;
        Bf[(size_t)t * 8 + j] = f2bf(W[k * 128 + n]);
    }
}

// ---------------- bin edges into padded buckets ----------------
__global__ __launch_bounds__(256) void k_bin(const int* __restrict__ esrc, const int* __restrict__ edst,
                                             int* bucket_cur, int2* __restrict__ binned) {
    __shared__ int cnt[NBUCKP];
    __shared__ int base[NBUCKP];
    int t = threadIdx.x;
    cnt[t] = 0;
    __syncthreads();
    int s[16], d[16], r[16];
    int e0 = blockIdx.x * 4096;
#pragma unroll
    for (int k = 0; k < 16; k++) {
        int e = e0 + k * 256 + t;
        if (e < N_EDGES) {
            s[k] = esrc[e];
            d[k] = edst[e];
            r[k] = atomicAdd(&cnt[d[k] >> 9], 1);
        } else {
            d[k] = -1;
        }
    }
    __syncthreads();
    base[t] = cnt[t] ? atomicAdd(&bucket_cur[t], cnt[t]) : 0;
    __syncthreads();
#pragma unroll
    for (int k = 0; k < 16; k++) {
        if (d[k] >= 0) {
            int bk = d[k] >> 9;
            int pos = base[bk] + r[k];
            if (pos < (bk + 1) * BUCK_CAP)
                binned[pos] = make_int2(s[k], d[k]);
        }
    }
}

// ---------------- per-bucket LDS counting sort -> row_ptr + col_src ----------------
__global__ __launch_bounds__(512) void k_sort(const int2* __restrict__ binned,
                                              const int* __restrict__ bucket_cur,
                                              int* __restrict__ row_ptr,
                                              int* __restrict__ col_src) {
    __shared__ int cnt[512];
    __shared__ int sm[512];
    int b = blockIdx.x, t = threadIdx.x;

    int partial = 0;
    if (t < b) partial = bucket_cur[t] - t * BUCK_CAP;
    sm[t] = partial;
    __syncthreads();
    for (int o = 256; o >= 1; o >>= 1) {
        if (t < o) sm[t] += sm[t + o];
        __syncthreads();
    }
    int base = sm[0];
    int n_e = bucket_cur[b] - b * BUCK_CAP;
    if (n_e > BUCK_CAP) n_e = BUCK_CAP;
    __syncthreads();

    cnt[t] = 0;
    __syncthreads();
    const int2* ebase = binned + (size_t)b * BUCK_CAP;
    for (int i = t; i < n_e; i += 512)
        atomicAdd(&cnt[ebase[i].y & 511], 1);
    __syncthreads();
    int v = cnt[t];
    sm[t] = v;
    __syncthreads();
    for (int o = 1; o < 512; o <<= 1) {
        int x = (t >= o) ? sm[t - o] : 0;
        __syncthreads();
        sm[t] += x;
        __syncthreads();
    }
    int excl = base + sm[t] - v;
    int node = b * 512 + t;
    if (node <= N_NODES) row_ptr[node] = excl;
    cnt[t] = excl;
    __syncthreads();
    for (int i = t; i < n_e; i += 512) {
        int2 sd = ebase[i];
        int p = atomicAdd(&cnt[sd.y & 511], 1);
        col_src[p] = sd.x;
    }
}

// ---------------- MFMA GEMM ----------------
// QUANT: biased-u8 row-quantized hq (u = q+128) + alsc[row] interleaved pairs
// {al_s[h], scale} x4 + al_d.
template<bool AF32, bool QUANT>
__global__ __launch_bounds__(256) void k_gemm(const void* __restrict__ Ap,
                                              const u16* __restrict__ Bf,
                                              u16* __restrict__ C,
                                              char* __restrict__ hq,
                                              float* __restrict__ alsc,
                                              const float* __restrict__ a_src,
                                              const float* __restrict__ a_dst,
                                              float* __restrict__ al_d, int M) {
    int wave = threadIdx.x >> 6, lane = threadIdx.x & 63;
    int quad = lane >> 4, l15 = lane & 15;
    int row0 = blockIdx.x * 64 + wave * 16;
    int m = row0 + l15;
    int mload = (m < M) ? m : (M - 1);

    short8 a[4];
    if (AF32) {
        const float* A = (const float*)Ap;
#pragma unroll
        for (int kk = 0; kk < 4; kk++) {
            const float* p = A + (size_t)mload * 128 + kk * 32 + quad * 8;
            float4 f0 = *(const float4*)p;
            float4 f1 = *(const float4*)(p + 4);
            short8 av;
            av[0] = (short)f2bf(f0.x); av[1] = (short)f2bf(f0.y);
            av[2] = (short)f2bf(f0.z); av[3] = (short)f2bf(f0.w);
            av[4] = (short)f2bf(f1.x); av[5] = (short)f2bf(f1.y);
            av[6] = (short)f2bf(f1.z); av[7] = (short)f2bf(f1.w);
            a[kk] = av;
        }
    } else {
        const u16* A = (const u16*)Ap;
#pragma unroll
        for (int kk = 0; kk < 4; kk++)
            a[kk] = *(const short8*)(A + (size_t)mload * 128 + kk * 32 + quad * 8);
    }

    float4v acc[8];
#pragma unroll
    for (int tn = 0; tn < 8; tn++) acc[tn] = (float4v){0.f, 0.f, 0.f, 0.f};

#pragma unroll
    for (int kk = 0; kk < 4; kk++) {
#pragma unroll
        for (int tn = 0; tn < 8; tn++) {
            short8 b = *(const short8*)(Bf + ((size_t)((kk * 8 + tn) * 64 + lane)) * 8);
            acc[tn] = __builtin_amdgcn_mfma_f32_16x16x32_bf16(a[kk], b, acc[tn], 0, 0, 0);
        }
    }

    float as0[4], as1[4], ad0[4], ad1[4];
    if (QUANT) {
#pragma unroll
        for (int hd = 0; hd < 4; hd++) {
            as0[hd] = a_src[hd * 32 + l15];
            as1[hd] = a_src[hd * 32 + 16 + l15];
            ad0[hd] = a_dst[hd * 32 + l15];
            ad1[hd] = a_dst[hd * 32 + 16 + l15];
        }
    }

#pragma unroll
    for (int rg = 0; rg < 4; rg++) {
        int gr = row0 + quad * 4 + rg;
        bool ok = (gr < M);
        if (!QUANT) {
            if (ok) {
#pragma unroll
                for (int tn = 0; tn < 8; tn++)
                    C[(size_t)gr * 128 + tn * 16 + l15] = f2bf(acc[tn][rg]);
            }
        } else {
            float amax = 0.f;
#pragma unroll
            for (int tn = 0; tn < 8; tn++) amax = fmaxf(amax, fabsf(acc[tn][rg]));
#pragma unroll
            for (int mm = 1; mm < 16; mm <<= 1) amax = fmaxf(amax, __shfl_xor(amax, mm, 64));
            float inv_s = (amax > 0.f) ? 127.f / amax : 0.f;
            if (ok) {
#pragma unroll
                for (int tn = 0; tn < 8; tn++) {
                    int q = (int)rintf(acc[tn][rg] * inv_s);
                    hq[(size_t)gr * 128 + tn * 16 + l15] = (char)(q + 128);   // biased u8
                }
            }
            float ps[4], pd[4];
#pragma unroll
            for (int hd = 0; hd < 4; hd++) {
                float c0 = acc[2 * hd][rg];
                float c1 = acc[2 * hd + 1][rg];
                ps[hd] = c0 * as0[hd] + c1 * as1[hd];
                pd[hd] = c0 * ad0[hd] + c1 * ad1[hd];
            }
#pragma unroll
            for (int mm = 1; mm < 16; mm <<= 1) {
#pragma unroll
                for (int hd = 0; hd < 4; hd++) {
                    ps[hd] += __shfl_xor(ps[hd], mm, 64);
                    pd[hd] += __shfl_xor(pd[hd], mm, 64);
                }
            }
            if (ok && l15 < 4) {
                float vs = (l15 == 0) ? ps[0] : (l15 == 1) ? ps[1] : (l15 == 2) ? ps[2] : ps[3];
                float vd = (l15 == 0) ? pd[0] : (l15 == 1) ? pd[1] : (l15 == 2) ? pd[2] : pd[3];
                alsc[(size_t)gr * 8 + l15 * 2]     = vs;                       // al_s[h]
                alsc[(size_t)gr * 8 + l15 * 2 + 1] = amax * (1.f / 127.f);     // scale (paired)
                al_d[gr * 4 + l15] = vd;
            }
        }
    }
}

// ---------------- fused aggregation: wide gather + perm/fma_mix decode (round-4 best) ----
// Chunk of 16 edges, fully unrolled, branch-free:
//  phase A (lane = slot*4 + head): one dwordx2 (al_s[h], scale) per (edge,head);
//    w = exp(leaky(.)); pad slots -> w=0; slots clamp to last edge (L1-hit pads).
//  phase B (16 lanes per edge, dwordx2/lane): 4 edges per VMEM; decode via
//    v_perm (biased u8 -> packed f16 = 1152+q, exact) + v_fma_mix_f32 (f32 acc).
template<bool XF32>
__global__ __launch_bounds__(256) void k_agg(const int* __restrict__ row_ptr, const int* __restrict__ col_src,
                      const float* __restrict__ alsc, const float* __restrict__ al_d,
                      const char* __restrict__ hq,
                      const void* __restrict__ xin, u16* __restrict__ xout) {
    int node = blockIdx.x * 4 + (threadIdx.x >> 6);
    int lane = threadIdx.x & 63;
    int l15 = lane & 15;
    int grp = lane >> 4;          // phase-B edge subgroup (0..3)
    int bh  = l15 >> 2;           // head of this lane's 8 dims
    int ae  = lane >> 2;          // phase-A edge slot (0..15)
    int ah  = lane & 3;           // phase-A head
    int beg = row_ptr[node], end = row_ptr[node + 1];
    int deg = end - beg;
    int degm1 = (deg > 0) ? deg - 1 : 0;
    float adst = al_d[node * 4 + ah];
    u32 loff = (u32)(l15 * 8);    // byte offset within a row

    float sw = 0.f, swl = 0.f;
    u32 h_one = 0x3C00u;          // f16 1.0
    float acc[8];
#pragma unroll
    for (int k = 0; k < 8; k++) acc[k] = 0.f;

    int nch = (deg + 15) >> 4;
    for (int cb = 0; cb < nch; cb++) {
        int c = cb * 16;
        int idx = c + l15;
        idx = (idx <= degm1) ? idx : degm1;          // clamp -> pad gathers reuse last line
        int sv = col_src[beg + idx];

        // ---- phase A: per-(slot,head) weight, one dwordx2
        int sA = __shfl(sv, ae, 64);
        float2 av = *(const float2*)(alsc + ((size_t)sA << 3) + (ah << 1));
        float ev = av.x + adst;
        ev = fmaxf(ev, 0.2f * ev);                   // leaky relu
        float w = __expf(ev);
        w = ((c + ae) < deg) ? w : 0.f;              // zero pad slots
        sw += w;
        float wsc = w * av.y;                        // fold src dequant scale

        // ---- phase B: 4 edges per iteration, dwordx2 gather + mix-precision MAC
#pragma unroll
        for (int i = 0; i < 4; i++) {
            int slot = 4 * i + grp;
            int s = __shfl(sv, slot, 64);
            float wl = __shfl(wsc, slot * 4 + bh, 64);
            u32 wlh;
            asm("v_cvt_f16_f32 %0, %1" : "=v"(wlh) : "v"(wl));
            FMIX_LO(swl, h_one, wlh);                // swl += f16(wl), f32 accum
            u32 off = ((u32)s << 7) + loff;
            uint2 hv = *(const uint2*)(hq + off);
            u32 p01 = __builtin_amdgcn_perm(0x64646464u, hv.x, 0x04010400u);
            u32 p23 = __builtin_amdgcn_perm(0x64646464u, hv.x, 0x04030402u);
            u32 p45 = __builtin_amdgcn_perm(0x64646464u, hv.y, 0x04010400u);
            u32 p67 = __builtin_amdgcn_perm(0x64646464u, hv.y, 0x04030402u);
            FMIX_LO(acc[0], p01, wlh); FMIX_HI(acc[1], p01, wlh);
            FMIX_LO(acc[2], p23, wlh); FMIX_HI(acc[3], p23, wlh);
            FMIX_LO(acc[4], p45, wlh); FMIX_HI(acc[5], p45, wlh);
            FMIX_LO(acc[6], p67, wlh); FMIX_HI(acc[7], p67, wlh);
        }
    }

    // remove the +1152 bias: acc_true = acc - 1152 * sum(wl)
#pragma unroll
    for (int k = 0; k < 8; k++) acc[k] = fmaf(swl, -1152.f, acc[k]);

    // sum(w): reduce over slot bits 2..5 (head preserved in bits 0..1)
#pragma unroll
    for (int mm = 4; mm < 64; mm <<= 1) sw += __shfl_xor(sw, mm, 64);
    float inv = 1.f / (__shfl(sw, bh, 64) + 1e-10f);

    // reduce accumulators across the 4 edge-subgroups (lane bits 4,5)
#pragma unroll
    for (int k = 0; k < 8; k++) {
        acc[k] += __shfl_xor(acc[k], 16, 64);
        acc[k] += __shfl_xor(acc[k], 32, 64);
    }

    if (grp == 0) {
        float r[8];
        if (XF32) {
            const float* x = (const float*)xin;
            float4 x0 = *(const float4*)&x[(size_t)node * 128 + l15 * 8];
            float4 x1 = *(const float4*)&x[(size_t)node * 128 + l15 * 8 + 4];
            r[0] = x0.x; r[1] = x0.y; r[2] = x0.z; r[3] = x0.w;
            r[4] = x1.x; r[5] = x1.y; r[6] = x1.z; r[7] = x1.w;
        } else {
            const u16* x = (const u16*)xin;
            short8 xv = *(const short8*)&x[(size_t)node * 128 + l15 * 8];
#pragma unroll
            for (int k = 0; k < 8; k++) r[k] = bf2f((u16)xv[k]);
        }
        u32 ow[4];
#pragma unroll
        for (int k = 0; k < 4; k++) {
            float a0 = acc[2 * k] * inv;
            float a1 = acc[2 * k + 1] * inv;
            a0 = (a0 > 0.f) ? a0 : (__expf(a0) - 1.f);
            a1 = (a1 > 0.f) ? a1 : (__expf(a1) - 1.f);
            ow[k] = (u32)f2bf(a0 + r[2 * k]) | ((u32)f2bf(a1 + r[2 * k + 1]) << 16);
        }
        *(uint4*)&xout[(size_t)node * 128 + l15 * 8] = make_uint4(ow[0], ow[1], ow[2], ow[3]);
    }
}

// ---------------- fused link predictor: gather-GEMM + relu + w2 dot ----------------
// Replaces DUAL gemm (z->uu,vv: 25.6MB read + 51.2MB write) + k_pair (51.2MB random
// read). Each wave handles 16 pairs: A1 = z[lsrc[...]], A2 = z[ldst[...]] gathered as
// MFMA A-fragments (same fragment math as k_gemm); acc = A1@W1a + A2@W1b (one shared
// accumulator - concat GEMM); epilogue: relu(acc + b1) . w2, quad-local shfl reduce.
__global__ __launch_bounds__(256) void k_link(const int* __restrict__ psrc, const int* __restrict__ pdst,
                                              const u16* __restrict__ z,
                                              const u16* __restrict__ BfA, const u16* __restrict__ BfB,
                                              const float* __restrict__ b1, const float* __restrict__ w2,
                                              const float* __restrict__ b2, float* __restrict__ out) {
    int wave = threadIdx.x >> 6, lane = threadIdx.x & 63;
    int quad = lane >> 4, l15 = lane & 15;
    int row0 = blockIdx.x * 64 + wave * 16;
    int prow = row0 + l15;
    int pload = (prow < N_PAIRS) ? prow : (N_PAIRS - 1);
    int s = psrc[pload], d = pdst[pload];

    // gather A-fragments: per pair-row, 4 quads cooperatively cover the 256B z row
    short8 a1[4], a2[4];
#pragma unroll
    for (int kk = 0; kk < 4; kk++) {
        a1[kk] = *(const short8*)(z + (size_t)s * 128 + kk * 32 + quad * 8);
        a2[kk] = *(const short8*)(z + (size_t)d * 128 + kk * 32 + quad * 8);
    }

    float4v acc[8];
#pragma unroll
    for (int tn = 0; tn < 8; tn++) acc[tn] = (float4v){0.f, 0.f, 0.f, 0.f};

#pragma unroll
    for (int kk = 0; kk < 4; kk++) {
#pragma unroll
        for (int tn = 0; tn < 8; tn++) {
            short8 ba = *(const short8*)(BfA + ((size_t)((kk * 8 + tn) * 64 + lane)) * 8);
            acc[tn] = __builtin_amdgcn_mfma_f32_16x16x32_bf16(a1[kk], ba, acc[tn], 0, 0, 0);
            short8 bb = *(const short8*)(BfB + ((size_t)((kk * 8 + tn) * 64 + lane)) * 8);
            acc[tn] = __builtin_amdgcn_mfma_f32_16x16x32_bf16(a2[kk], bb, acc[tn], 0, 0, 0);
        }
    }

    float b1v[8], w2v[8];
#pragma unroll
    for (int tn = 0; tn < 8; tn++) {
        b1v[tn] = b1[tn * 16 + l15];
        w2v[tn] = w2[tn * 16 + l15];
    }
    float bb2 = b2[0];

#pragma unroll
    for (int rg = 0; rg < 4; rg++) {
        float part = 0.f;
#pragma unroll
        for (int tn = 0; tn < 8; tn++) {
            float h = acc[tn][rg] + b1v[tn];
            h = (h > 0.f) ? h : 0.f;
            part += h * w2v[tn];
        }
        // reduce over the 16 cols (lane bits 0..3, within quad)
#pragma unroll
        for (int mm = 1; mm < 16; mm <<= 1) part += __shfl_xor(part, mm, 64);
        int gr = row0 + quad * 4 + rg;
        if (l15 == 0 && gr < N_PAIRS) out[gr] = part + bb2;
    }
}

extern "C" void kernel_launch(void* const* d_in, const int* in_sizes, int n_in,
                              void* d_out, int out_size, void* d_ws, size_t ws_size,
                              hipStream_t stream) {
    const float* embed  = (const float*)d_in[0];
    const float* W1     = (const float*)d_in[1];
    const float* a_src1 = (const float*)d_in[2];
    const float* a_dst1 = (const float*)d_in[3];
    const float* W2     = (const float*)d_in[4];
    const float* a_src2 = (const float*)d_in[5];
    const float* a_dst2 = (const float*)d_in[6];
    const float* lp_w1  = (const float*)d_in[7];
    const float* lp_b1  = (const float*)d_in[8];
    const float* lp_w2  = (const float*)d_in[9];
    const float* lp_b2  = (const float*)d_in[10];
    const int*   edge   = (const int*)d_in[11];
    const int*   lsrc   = (const int*)d_in[12];
    const int*   ldst   = (const int*)d_in[13];
    float* out = (float*)d_out;

    char* ws = (char*)d_ws;
    size_t off = 0;
    auto alloc = [&](size_t bytes) -> char* {
        char* p = ws + off;
        off += (bytes + 255) & ~(size_t)255;
        return p;
    };
    int*  row_ptr    = (int*)alloc((N_NODES + 1) * 4);
    int*  bucket_cur = (int*)alloc(NBUCKP * 4);
    int2* binned     = (int2*)alloc((size_t)NBUCKP * BUCK_CAP * 8);
    int*  col_src    = (int*)alloc((size_t)N_EDGES * 4);
    char* hq         = (char*)alloc((size_t)N_NODES * 128);
    float* alsc      = (float*)alloc((size_t)N_NODES * 8 * 4);
    float* al_d      = (float*)alloc((size_t)N_NODES * 4 * 4);
    u16*  x1         = (u16*)alloc((size_t)N_NODES * 128 * 2);
    u16*  z          = (u16*)alloc((size_t)N_NODES * 128 * 2);
    u16*  Bf1        = (u16*)alloc(128 * 128 * 2);
    u16*  Bf2        = (u16*)alloc(128 * 128 * 2);
    u16*  BfA        = (u16*)alloc(128 * 128 * 2);
    u16*  BfB        = (u16*)alloc(128 * 128 * 2);

    const int* esrc = edge;
    const int* edst = edge + N_EDGES;
    const int GB = (N_NODES + 63) / 64;
    const int GP = (N_PAIRS + 63) / 64;

    k_prepB4<<<33, 256, 0, stream>>>(W1, W2, lp_w1, lp_w1 + 128 * 128, Bf1, Bf2, BfA, BfB, bucket_cur);

    k_bin <<<BIN_GRID, 256, 0, stream>>>(esrc, edst, bucket_cur, binned);
    k_sort<<<NB_USED, 512, 0, stream>>>(binned, bucket_cur, row_ptr, col_src);

    // layer 1: hq = u8(embed @ W1), fused alpha+scale pack
    k_gemm<true, true><<<GB, 256, 0, stream>>>(embed, Bf1, nullptr,
                                               hq, alsc, a_src1, a_dst1, al_d, N_NODES);
    k_agg<true><<<N_NODES / 4, 256, 0, stream>>>(row_ptr, col_src, alsc, al_d, hq, embed, x1);
    // layer 2
    k_gemm<false, true><<<GB, 256, 0, stream>>>(x1, Bf2, nullptr,
                                                hq, alsc, a_src2, a_dst2, al_d, N_NODES);
    k_agg<false><<<N_NODES / 4, 256, 0, stream>>>(row_ptr, col_src, alsc, al_d, hq, x1, z);
    // fused link predictor (replaces DUAL gemm + k_pair)
    k_link<<<GP, 256, 0, stream>>>(lsrc, ldst, z, BfA, BfB, lp_b1, lp_w2, lp_b2, out);
}

// Round 8
// 325.963 us; speedup vs baseline: 1.0999x; 1.0084x over previous
//
#include <hip/hip_runtime.h>

typedef unsigned short u16;
typedef unsigned int u32;
typedef __attribute__((ext_vector_type(8))) short short8;
typedef __attribute__((ext_vector_type(4))) float float4v;

#define N_NODES 100000
#define N_EDGES 1600000
#define N_PAIRS 100000
#define NBUCK 391            // buckets of 256 nodes (dst>>8); 391*256 = 100096
#define BUCK_CAP 4608        // mean 4096, sigma~64 -> +8 sigma; = 18*256 exactly
#define BIN_GRID 391

__device__ __forceinline__ float bf2f(u32 lo16) {
    union { u32 u; float f; } v;
    v.u = lo16 << 16;
    return v.f;
}
__device__ __forceinline__ u16 f2bf(float f) {
    union { float f; u32 u; } v;
    v.f = f;
    u32 r = v.u + 0x7fffu + ((v.u >> 16) & 1u);
    return (u16)(r >> 16);
}

// f16-pair decode + mixed-precision MAC:
//  Q = v_perm packed (0x6400|u1,0x6400|u0) = f16 values (1152+q1, 1152+q0), exact.
//  v_fma_mix_f32: acc(f32) += f16(Q half) * f16(W lo). Offset removed via swl.
#define FMIX_LO(A, Q, W) asm("v_fma_mix_f32 %0, %1, %2, %0 op_sel:[0,0,0] op_sel_hi:[1,1,0]" : "+v"(A) : "v"(Q), "v"(W))
#define FMIX_HI(A, Q, W) asm("v_fma_mix_f32 %0, %1, %2, %0 op_sel:[1,0,0] op_sel_hi:[1,1,0]" : "+v"(A) : "v"(Q), "v"(W))

// ---------------- pre-swizzle weights + init bucket cursors (block 32) ----------------
__global__ __launch_bounds__(256) void k_prepB4(const float* __restrict__ W1, const float* __restrict__ W2,
                                                const float* __restrict__ WA, const float* __restrict__ WB,
                                                u16* __restrict__ B1, u16* __restrict__ B2,
                                                u16* __restrict__ BA, u16* __restrict__ BB,
                                                int* __restrict__ bucket_cur) {
    if (blockIdx.x == 32) {
        for (int i = threadIdx.x; i < NBUCK; i += 256)
            bucket_cur[i] = i * BUCK_CAP;
        return;
    }
    int w = blockIdx.x >> 3;
    const float* W = (w == 0) ? W1 : (w == 1) ? W2 : (w == 2) ? WA : WB;
    u16* Bf = (w == 0) ? B1 : (w == 1) ? B2 : (w == 2) ? BA : BB;
    int t = (blockIdx.x & 7) * 256 + threadIdx.x;
    int kk = t >> 9, tn = (t >> 6) & 7, quad = (t >> 4) & 3, l15 = t & 15;
#pragma unroll
    for (int j = 0; j < 8; j++) {
        int k = kk * 32 + quad * 8 + j;
        int n = tn * 16 + l15;
        Bf[(size_t)t * 8 + j] = f2bf(W[k * 128 + n]);
    }
}

// ---------------- bin edges into padded buckets (packed u32: src<<8 | dst&255) ------
__global__ __launch_bounds__(256) void k_bin(const int* __restrict__ esrc, const int* __restrict__ edst,
                                             int* bucket_cur, u32* __restrict__ binned) {
    __shared__ int cnt[NBUCK];
    __shared__ int base[NBUCK];
    int t = threadIdx.x;
    for (int i = t; i < NBUCK; i += 256) cnt[i] = 0;
    __syncthreads();
    int s[16], d[16], r[16];
    int e0 = blockIdx.x * 4096;
#pragma unroll
    for (int k = 0; k < 16; k++) {
        int e = e0 + k * 256 + t;
        if (e < N_EDGES) {
            s[k] = esrc[e];
            d[k] = edst[e];
            r[k] = atomicAdd(&cnt[d[k] >> 8], 1);
        } else {
            d[k] = -1;
        }
    }
    __syncthreads();
    for (int i = t; i < NBUCK; i += 256)
        base[i] = cnt[i] ? atomicAdd(&bucket_cur[i], cnt[i]) : 0;
    __syncthreads();
#pragma unroll
    for (int k = 0; k < 16; k++) {
        if (d[k] >= 0) {
            int bk = d[k] >> 8;
            int pos = base[bk] + r[k];
            if (pos < (bk + 1) * BUCK_CAP)
                binned[pos] = ((u32)s[k] << 8) | ((u32)d[k] & 255u);
        }
    }
}

// ---------------- per-bucket LDS counting sort -> row_ptr + col_src ----------------
// 391 blocks x 256 threads (was 196x512): >1 block/CU. Edges held in registers
// (<=18/thread, statically unrolled) across count -> scan -> scatter: single
// binned read. Packed u32 halves traffic.
__global__ __launch_bounds__(256) void k_sort(const u32* __restrict__ binned,
                                              const int* __restrict__ bucket_cur,
                                              int* __restrict__ row_ptr,
                                              int* __restrict__ col_src) {
    __shared__ int cnt[256];
    __shared__ int sm[256];
    int b = blockIdx.x, t = threadIdx.x;

    int partial = 0;
    for (int i = t; i < b; i += 256) {
        int c = bucket_cur[i] - i * BUCK_CAP;
        partial += (c > BUCK_CAP) ? BUCK_CAP : c;
    }
    sm[t] = partial;
    __syncthreads();
    for (int o = 128; o >= 1; o >>= 1) {
        if (t < o) sm[t] += sm[t + o];
        __syncthreads();
    }
    int base = sm[0];
    int n_e = bucket_cur[b] - b * BUCK_CAP;
    if (n_e > BUCK_CAP) n_e = BUCK_CAP;
    __syncthreads();

    cnt[t] = 0;
    __syncthreads();
    const u32* ebase = binned + (size_t)b * BUCK_CAP;
    u32 ed[18];
#pragma unroll
    for (int j = 0; j < 18; j++) {
        int i = t + j * 256;
        ed[j] = (i < n_e) ? ebase[i] : 0xFFFFFFFFu;
        if (ed[j] != 0xFFFFFFFFu) atomicAdd(&cnt[ed[j] & 255u], 1);
    }
    __syncthreads();
    int v = cnt[t];
    sm[t] = v;
    __syncthreads();
    for (int o = 1; o < 256; o <<= 1) {
        int x = (t >= o) ? sm[t - o] : 0;
        __syncthreads();
        sm[t] += x;
        __syncthreads();
    }
    int excl = base + sm[t] - v;
    int node = b * 256 + t;
    if (node <= N_NODES) row_ptr[node] = excl;
    cnt[t] = excl;
    __syncthreads();
#pragma unroll
    for (int j = 0; j < 18; j++) {
        if (ed[j] != 0xFFFFFFFFu) {
            int p = atomicAdd(&cnt[ed[j] & 255u], 1);
            col_src[p] = (int)(ed[j] >> 8);
        }
    }
}

// ---------------- MFMA GEMM ----------------
// QUANT: biased-u8 row-quantized hq (u = q+128) + alsc[row] interleaved pairs
// {al_s[h], scale} x4 + al_d.
template<bool AF32, bool QUANT>
__global__ __launch_bounds__(256) void k_gemm(const void* __restrict__ Ap,
                                              const u16* __restrict__ Bf,
                                              u16* __restrict__ C,
                                              char* __restrict__ hq,
                                              float* __restrict__ alsc,
                                              const float* __restrict__ a_src,
                                              const float* __restrict__ a_dst,
                                              float* __restrict__ al_d, int M) {
    int wave = threadIdx.x >> 6, lane = threadIdx.x & 63;
    int quad = lane >> 4, l15 = lane & 15;
    int row0 = blockIdx.x * 64 + wave * 16;
    int m = row0 + l15;
    int mload = (m < M) ? m : (M - 1);

    short8 a[4];
    if (AF32) {
        const float* A = (const float*)Ap;
#pragma unroll
        for (int kk = 0; kk < 4; kk++) {
            const float* p = A + (size_t)mload * 128 + kk * 32 + quad * 8;
            float4 f0 = *(const float4*)p;
            float4 f1 = *(const float4*)(p + 4);
            short8 av;
            av[0] = (short)f2bf(f0.x); av[1] = (short)f2bf(f0.y);
            av[2] = (short)f2bf(f0.z); av[3] = (short)f2bf(f0.w);
            av[4] = (short)f2bf(f1.x); av[5] = (short)f2bf(f1.y);
            av[6] = (short)f2bf(f1.z); av[7] = (short)f2bf(f1.w);
            a[kk] = av;
        }
    } else {
        const u16* A = (const u16*)Ap;
#pragma unroll
        for (int kk = 0; kk < 4; kk++)
            a[kk] = *(const short8*)(A + (size_t)mload * 128 + kk * 32 + quad * 8);
    }

    float4v acc[8];
#pragma unroll
    for (int tn = 0; tn < 8; tn++) acc[tn] = (float4v){0.f, 0.f, 0.f, 0.f};

#pragma unroll
    for (int kk = 0; kk < 4; kk++) {
#pragma unroll
        for (int tn = 0; tn < 8; tn++) {
            short8 b = *(const short8*)(Bf + ((size_t)((kk * 8 + tn) * 64 + lane)) * 8);
            acc[tn] = __builtin_amdgcn_mfma_f32_16x16x32_bf16(a[kk], b, acc[tn], 0, 0, 0);
        }
    }

    float as0[4], as1[4], ad0[4], ad1[4];
    if (QUANT) {
#pragma unroll
        for (int hd = 0; hd < 4; hd++) {
            as0[hd] = a_src[hd * 32 + l15];
            as1[hd] = a_src[hd * 32 + 16 + l15];
            ad0[hd] = a_dst[hd * 32 + l15];
            ad1[hd] = a_dst[hd * 32 + 16 + l15];
        }
    }

#pragma unroll
    for (int rg = 0; rg < 4; rg++) {
        int gr = row0 + quad * 4 + rg;
        bool ok = (gr < M);
        if (!QUANT) {
            if (ok) {
#pragma unroll
                for (int tn = 0; tn < 8; tn++)
                    C[(size_t)gr * 128 + tn * 16 + l15] = f2bf(acc[tn][rg]);
            }
        } else {
            float amax = 0.f;
#pragma unroll
            for (int tn = 0; tn < 8; tn++) amax = fmaxf(amax, fabsf(acc[tn][rg]));
#pragma unroll
            for (int mm = 1; mm < 16; mm <<= 1) amax = fmaxf(amax, __shfl_xor(amax, mm, 64));
            float inv_s = (amax > 0.f) ? 127.f / amax : 0.f;
            if (ok) {
#pragma unroll
                for (int tn = 0; tn < 8; tn++) {
                    int q = (int)rintf(acc[tn][rg] * inv_s);
                    hq[(size_t)gr * 128 + tn * 16 + l15] = (char)(q + 128);   // biased u8
                }
            }
            float ps[4], pd[4];
#pragma unroll
            for (int hd = 0; hd < 4; hd++) {
                float c0 = acc[2 * hd][rg];
                float c1 = acc[2 * hd + 1][rg];
                ps[hd] = c0 * as0[hd] + c1 * as1[hd];
                pd[hd] = c0 * ad0[hd] + c1 * ad1[hd];
            }
#pragma unroll
            for (int mm = 1; mm < 16; mm <<= 1) {
#pragma unroll
                for (int hd = 0; hd < 4; hd++) {
                    ps[hd] += __shfl_xor(ps[hd], mm, 64);
                    pd[hd] += __shfl_xor(pd[hd], mm, 64);
                }
            }
            if (ok && l15 < 4) {
                float vs = (l15 == 0) ? ps[0] : (l15 == 1) ? ps[1] : (l15 == 2) ? ps[2] : ps[3];
                float vd = (l15 == 0) ? pd[0] : (l15 == 1) ? pd[1] : (l15 == 2) ? pd[2] : pd[3];
                alsc[(size_t)gr * 8 + l15 * 2]     = vs;                       // al_s[h]
                alsc[(size_t)gr * 8 + l15 * 2 + 1] = amax * (1.f / 127.f);     // scale (paired)
                al_d[gr * 4 + l15] = vd;
            }
        }
    }
}

// ---------------- fused aggregation: wide gather + perm/fma_mix decode (round-4 best) ----
template<bool XF32>
__global__ __launch_bounds__(256) void k_agg(const int* __restrict__ row_ptr, const int* __restrict__ col_src,
                      const float* __restrict__ alsc, const float* __restrict__ al_d,
                      const char* __restrict__ hq,
                      const void* __restrict__ xin, u16* __restrict__ xout) {
    int node = blockIdx.x * 4 + (threadIdx.x >> 6);
    int lane = threadIdx.x & 63;
    int l15 = lane & 15;
    int grp = lane >> 4;          // phase-B edge subgroup (0..3)
    int bh  = l15 >> 2;           // head of this lane's 8 dims
    int ae  = lane >> 2;          // phase-A edge slot (0..15)
    int ah  = lane & 3;           // phase-A head
    int beg = row_ptr[node], end = row_ptr[node + 1];
    int deg = end - beg;
    int degm1 = (deg > 0) ? deg - 1 : 0;
    float adst = al_d[node * 4 + ah];
    u32 loff = (u32)(l15 * 8);    // byte offset within a row

    float sw = 0.f, swl = 0.f;
    u32 h_one = 0x3C00u;          // f16 1.0
    float acc[8];
#pragma unroll
    for (int k = 0; k < 8; k++) acc[k] = 0.f;

    int nch = (deg + 15) >> 4;
    for (int cb = 0; cb < nch; cb++) {
        int c = cb * 16;
        int idx = c + l15;
        idx = (idx <= degm1) ? idx : degm1;          // clamp -> pad gathers reuse last line
        int sv = col_src[beg + idx];

        // ---- phase A: per-(slot,head) weight, one dwordx2
        int sA = __shfl(sv, ae, 64);
        float2 av = *(const float2*)(alsc + ((size_t)sA << 3) + (ah << 1));
        float ev = av.x + adst;
        ev = fmaxf(ev, 0.2f * ev);                   // leaky relu
        float w = __expf(ev);
        w = ((c + ae) < deg) ? w : 0.f;              // zero pad slots
        sw += w;
        float wsc = w * av.y;                        // fold src dequant scale

        // ---- phase B: 4 edges per iteration, dwordx2 gather + mix-precision MAC
#pragma unroll
        for (int i = 0; i < 4; i++) {
            int slot = 4 * i + grp;
            int s = __shfl(sv, slot, 64);
            float wl = __shfl(wsc, slot * 4 + bh, 64);
            u32 wlh;
            asm("v_cvt_f16_f32 %0, %1" : "=v"(wlh) : "v"(wl));
            FMIX_LO(swl, h_one, wlh);                // swl += f16(wl), f32 accum
            u32 off = ((u32)s << 7) + loff;
            uint2 hv = *(const uint2*)(hq + off);
            u32 p01 = __builtin_amdgcn_perm(0x64646464u, hv.x, 0x04010400u);
            u32 p23 = __builtin_amdgcn_perm(0x64646464u, hv.x, 0x04030402u);
            u32 p45 = __builtin_amdgcn_perm(0x64646464u, hv.y, 0x04010400u);
            u32 p67 = __builtin_amdgcn_perm(0x64646464u, hv.y, 0x04030402u);
            FMIX_LO(acc[0], p01, wlh); FMIX_HI(acc[1], p01, wlh);
            FMIX_LO(acc[2], p23, wlh); FMIX_HI(acc[3], p23, wlh);
            FMIX_LO(acc[4], p45, wlh); FMIX_HI(acc[5], p45, wlh);
            FMIX_LO(acc[6], p67, wlh); FMIX_HI(acc[7], p67, wlh);
        }
    }

    // remove the +1152 bias: acc_true = acc - 1152 * sum(wl)
#pragma unroll
    for (int k = 0; k < 8; k++) acc[k] = fmaf(swl, -1152.f, acc[k]);

    // sum(w): reduce over slot bits 2..5 (head preserved in bits 0..1)
#pragma unroll
    for (int mm = 4; mm < 64; mm <<= 1) sw += __shfl_xor(sw, mm, 64);
    float inv = 1.f / (__shfl(sw, bh, 64) + 1e-10f);

    // reduce accumulators across the 4 edge-subgroups (lane bits 4,5)
#pragma unroll
    for (int k = 0; k < 8; k++) {
        acc[k] += __shfl_xor(acc[k], 16, 64);
        acc[k] += __shfl_xor(acc[k], 32, 64);
    }

    if (grp == 0) {
        float r[8];
        if (XF32) {
            const float* x = (const float*)xin;
            float4 x0 = *(const float4*)&x[(size_t)node * 128 + l15 * 8];
            float4 x1 = *(const float4*)&x[(size_t)node * 128 + l15 * 8 + 4];
            r[0] = x0.x; r[1] = x0.y; r[2] = x0.z; r[3] = x0.w;
            r[4] = x1.x; r[5] = x1.y; r[6] = x1.z; r[7] = x1.w;
        } else {
            const u16* x = (const u16*)xin;
            short8 xv = *(const short8*)&x[(size_t)node * 128 + l15 * 8];
#pragma unroll
            for (int k = 0; k < 8; k++) r[k] = bf2f((u16)xv[k]);
        }
        u32 ow[4];
#pragma unroll
        for (int k = 0; k < 4; k++) {
            float a0 = acc[2 * k] * inv;
            float a1 = acc[2 * k + 1] * inv;
            a0 = (a0 > 0.f) ? a0 : (__expf(a0) - 1.f);
            a1 = (a1 > 0.f) ? a1 : (__expf(a1) - 1.f);
            ow[k] = (u32)f2bf(a0 + r[2 * k]) | ((u32)f2bf(a1 + r[2 * k + 1]) << 16);
        }
        *(uint4*)&xout[(size_t)node * 128 + l15 * 8] = make_uint4(ow[0], ow[1], ow[2], ow[3]);
    }
}

// ---------------- fused link predictor: gather-GEMM + relu + w2 dot ----------------
__global__ __launch_bounds__(256) void k_link(const int* __restrict__ psrc, const int* __restrict__ pdst,
                                              const u16* __restrict__ z,
                                              const u16* __restrict__ BfA, const u16* __restrict__ BfB,
                                              const float* __restrict__ b1, const float* __restrict__ w2,
                                              const float* __restrict__ b2, float* __restrict__ out) {
    int wave = threadIdx.x >> 6, lane = threadIdx.x & 63;
    int quad = lane >> 4, l15 = lane & 15;
    int row0 = blockIdx.x * 64 + wave * 16;
    int prow = row0 + l15;
    int pload = (prow < N_PAIRS) ? prow : (N_PAIRS - 1);
    int s = psrc[pload], d = pdst[pload];

    // gather A-fragments: per pair-row, 4 quads cooperatively cover the 256B z row
    short8 a1[4], a2[4];
#pragma unroll
    for (int kk = 0; kk < 4; kk++) {
        a1[kk] = *(const short8*)(z + (size_t)s * 128 + kk * 32 + quad * 8);
        a2[kk] = *(const short8*)(z + (size_t)d * 128 + kk * 32 + quad * 8);
    }

    float4v acc[8];
#pragma unroll
    for (int tn = 0; tn < 8; tn++) acc[tn] = (float4v){0.f, 0.f, 0.f, 0.f};

#pragma unroll
    for (int kk = 0; kk < 4; kk++) {
#pragma unroll
        for (int tn = 0; tn < 8; tn++) {
            short8 ba = *(const short8*)(BfA + ((size_t)((kk * 8 + tn) * 64 + lane)) * 8);
            acc[tn] = __builtin_amdgcn_mfma_f32_16x16x32_bf16(a1[kk], ba, acc[tn], 0, 0, 0);
            short8 bb = *(const short8*)(BfB + ((size_t)((kk * 8 + tn) * 64 + lane)) * 8);
            acc[tn] = __builtin_amdgcn_mfma_f32_16x16x32_bf16(a2[kk], bb, acc[tn], 0, 0, 0);
        }
    }

    float b1v[8], w2v[8];
#pragma unroll
    for (int tn = 0; tn < 8; tn++) {
        b1v[tn] = b1[tn * 16 + l15];
        w2v[tn] = w2[tn * 16 + l15];
    }
    float bb2 = b2[0];

#pragma unroll
    for (int rg = 0; rg < 4; rg++) {
        float part = 0.f;
#pragma unroll
        for (int tn = 0; tn < 8; tn++) {
            float h = acc[tn][rg] + b1v[tn];
            h = (h > 0.f) ? h : 0.f;
            part += h * w2v[tn];
        }
        // reduce over the 16 cols (lane bits 0..3, within quad)
#pragma unroll
        for (int mm = 1; mm < 16; mm <<= 1) part += __shfl_xor(part, mm, 64);
        int gr = row0 + quad * 4 + rg;
        if (l15 == 0 && gr < N_PAIRS) out[gr] = part + bb2;
    }
}

extern "C" void kernel_launch(void* const* d_in, const int* in_sizes, int n_in,
                              void* d_out, int out_size, void* d_ws, size_t ws_size,
                              hipStream_t stream) {
    const float* embed  = (const float*)d_in[0];
    const float* W1     = (const float*)d_in[1];
    const float* a_src1 = (const float*)d_in[2];
    const float* a_dst1 = (const float*)d_in[3];
    const float* W2     = (const float*)d_in[4];
    const float* a_src2 = (const float*)d_in[5];
    const float* a_dst2 = (const float*)d_in[6];
    const float* lp_w1  = (const float*)d_in[7];
    const float* lp_b1  = (const float*)d_in[8];
    const float* lp_w2  = (const float*)d_in[9];
    const float* lp_b2  = (const float*)d_in[10];
    const int*   edge   = (const int*)d_in[11];
    const int*   lsrc   = (const int*)d_in[12];
    const int*   ldst   = (const int*)d_in[13];
    float* out = (float*)d_out;

    char* ws = (char*)d_ws;
    size_t off = 0;
    auto alloc = [&](size_t bytes) -> char* {
        char* p = ws + off;
        off += (bytes + 255) & ~(size_t)255;
        return p;
    };
    int*  row_ptr    = (int*)alloc((N_NODES + 1) * 4);
    int*  bucket_cur = (int*)alloc(512 * 4);
    u32*  binned     = (u32*)alloc((size_t)NBUCK * BUCK_CAP * 4);
    int*  col_src    = (int*)alloc((size_t)N_EDGES * 4);
    char* hq         = (char*)alloc((size_t)N_NODES * 128);
    float* alsc      = (float*)alloc((size_t)N_NODES * 8 * 4);
    float* al_d      = (float*)alloc((size_t)N_NODES * 4 * 4);
    u16*  x1         = (u16*)alloc((size_t)N_NODES * 128 * 2);
    u16*  z          = (u16*)alloc((size_t)N_NODES * 128 * 2);
    u16*  Bf1        = (u16*)alloc(128 * 128 * 2);
    u16*  Bf2        = (u16*)alloc(128 * 128 * 2);
    u16*  BfA        = (u16*)alloc(128 * 128 * 2);
    u16*  BfB        = (u16*)alloc(128 * 128 * 2);

    const int* esrc = edge;
    const int* edst = edge + N_EDGES;
    const int GB = (N_NODES + 63) / 64;
    const int GP = (N_PAIRS + 63) / 64;

    k_prepB4<<<33, 256, 0, stream>>>(W1, W2, lp_w1, lp_w1 + 128 * 128, Bf1, Bf2, BfA, BfB, bucket_cur);

    k_bin <<<BIN_GRID, 256, 0, stream>>>(esrc, edst, bucket_cur, binned);
    k_sort<<<NBUCK, 256, 0, stream>>>(binned, bucket_cur, row_ptr, col_src);

    // layer 1: hq = u8(embed @ W1), fused alpha+scale pack
    k_gemm<true, true><<<GB, 256, 0, stream>>>(embed, Bf1, nullptr,
                                               hq, alsc, a_src1, a_dst1, al_d, N_NODES);
    k_agg<true><<<N_NODES / 4, 256, 0, stream>>>(row_ptr, col_src, alsc, al_d, hq, embed, x1);
    // layer 2
    k_gemm<false, true><<<GB, 256, 0, stream>>>(x1, Bf2, nullptr,
                                                hq, alsc, a_src2, a_dst2, al_d, N_NODES);
    k_agg<false><<<N_NODES / 4, 256, 0, stream>>>(row_ptr, col_src, alsc, al_d, hq, x1, z);
    // fused link predictor (replaces DUAL gemm + k_pair)
    k_link<<<GP, 256, 0, stream>>>(lsrc, ldst, z, BfA, BfB, lp_b1, lp_w2, lp_b2, out);
}

// Round 9
// 325.190 us; speedup vs baseline: 1.1026x; 1.0024x over previous
//
#include <hip/hip_runtime.h>

typedef unsigned short u16;
typedef unsigned int u32;
typedef __attribute__((ext_vector_type(8))) short short8;
typedef __attribute__((ext_vector_type(4))) float float4v;

#define N_NODES 100000
#define N_EDGES 1600000
#define N_PAIRS 100000
#define NBUCK 391            // buckets of 256 nodes (dst>>8); 391*256 = 100096
#define BUCK_CAP 4608        // mean 4096, sigma~64 -> +8 sigma; = 18*256 exactly
#define BIN_GRID 391

__device__ __forceinline__ float bf2f(u32 lo16) {
    union { u32 u; float f; } v;
    v.u = lo16 << 16;
    return v.f;
}
__device__ __forceinline__ u16 f2bf(float f) {
    union { float f; u32 u; } v;
    v.f = f;
    u32 r = v.u + 0x7fffu + ((v.u >> 16) & 1u);
    return (u16)(r >> 16);
}

// f16-pair decode + mixed-precision MAC:
//  Q = v_perm packed (0x6400|u1,0x6400|u0) = f16 values (1152+q1, 1152+q0), exact.
//  v_fma_mix_f32: acc(f32) += f16(Q half) * f16(W lo). Offset removed via swl.
#define FMIX_LO(A, Q, W) asm("v_fma_mix_f32 %0, %1, %2, %0 op_sel:[0,0,0] op_sel_hi:[1,1,0]" : "+v"(A) : "v"(Q), "v"(W))
#define FMIX_HI(A, Q, W) asm("v_fma_mix_f32 %0, %1, %2, %0 op_sel:[1,0,0] op_sel_hi:[1,1,0]" : "+v"(A) : "v"(Q), "v"(W))

// ---------------- device bodies -------------------------------------------------

// weight pre-swizzle: blocks 0..31 (w = blk>>3, 8 blocks per matrix)
__device__ __forceinline__ void prep_body(int blk, int tid,
                                          const float* __restrict__ W1, const float* __restrict__ W2,
                                          const float* __restrict__ WA, const float* __restrict__ WB,
                                          u16* __restrict__ B1, u16* __restrict__ B2,
                                          u16* __restrict__ BA, u16* __restrict__ BB) {
    int w = blk >> 3;
    const float* W = (w == 0) ? W1 : (w == 1) ? W2 : (w == 2) ? WA : WB;
    u16* Bf = (w == 0) ? B1 : (w == 1) ? B2 : (w == 2) ? BA : BB;
    int t = (blk & 7) * 256 + tid;
    int kk = t >> 9, tn = (t >> 6) & 7, quad = (t >> 4) & 3, l15 = t & 15;
#pragma unroll
    for (int j = 0; j < 8; j++) {
        int k = kk * 32 + quad * 8 + j;
        int n = tn * 16 + l15;
        Bf[(size_t)t * 8 + j] = f2bf(W[k * 128 + n]);
    }
}

// bin edges into padded buckets (packed u32: src<<8 | dst&255); zero-based cursors
__device__ __forceinline__ void bin_body(int blk, int t,
                                         const int* __restrict__ esrc, const int* __restrict__ edst,
                                         int* bucket_cur, u32* __restrict__ binned) {
    __shared__ int cnt[NBUCK];
    __shared__ int base[NBUCK];
    for (int i = t; i < NBUCK; i += 256) cnt[i] = 0;
    __syncthreads();
    int s[16], d[16], r[16];
    int e0 = blk * 4096;
#pragma unroll
    for (int k = 0; k < 16; k++) {
        int e = e0 + k * 256 + t;
        if (e < N_EDGES) {
            s[k] = esrc[e];
            d[k] = edst[e];
            r[k] = atomicAdd(&cnt[d[k] >> 8], 1);
        } else {
            d[k] = -1;
        }
    }
    __syncthreads();
    for (int i = t; i < NBUCK; i += 256)
        base[i] = cnt[i] ? atomicAdd(&bucket_cur[i], cnt[i]) : 0;
    __syncthreads();
#pragma unroll
    for (int k = 0; k < 16; k++) {
        if (d[k] >= 0) {
            int bk = d[k] >> 8;
            int pos = base[bk] + r[k];
            if (pos < BUCK_CAP)
                binned[(size_t)bk * BUCK_CAP + pos] = ((u32)s[k] << 8) | ((u32)d[k] & 255u);
        }
    }
}

// per-bucket LDS counting sort -> row_ptr + col_src (zero-based cursors)
__device__ __forceinline__ void sort_body(int b, int t,
                                          const u32* __restrict__ binned,
                                          const int* __restrict__ bucket_cur,
                                          int* __restrict__ row_ptr,
                                          int* __restrict__ col_src) {
    __shared__ int cnt[256];
    __shared__ int sm[256];

    int partial = 0;
    for (int i = t; i < b; i += 256) {
        int c = bucket_cur[i];
        partial += (c > BUCK_CAP) ? BUCK_CAP : c;
    }
    sm[t] = partial;
    __syncthreads();
    for (int o = 128; o >= 1; o >>= 1) {
        if (t < o) sm[t] += sm[t + o];
        __syncthreads();
    }
    int base = sm[0];
    int n_e = bucket_cur[b];
    if (n_e > BUCK_CAP) n_e = BUCK_CAP;
    __syncthreads();

    cnt[t] = 0;
    __syncthreads();
    const u32* ebase = binned + (size_t)b * BUCK_CAP;
    u32 ed[18];
#pragma unroll
    for (int j = 0; j < 18; j++) {
        int i = t + j * 256;
        ed[j] = (i < n_e) ? ebase[i] : 0xFFFFFFFFu;
        if (ed[j] != 0xFFFFFFFFu) atomicAdd(&cnt[ed[j] & 255u], 1);
    }
    __syncthreads();
    int v = cnt[t];
    sm[t] = v;
    __syncthreads();
    for (int o = 1; o < 256; o <<= 1) {
        int x = (t >= o) ? sm[t - o] : 0;
        __syncthreads();
        sm[t] += x;
        __syncthreads();
    }
    int excl = base + sm[t] - v;
    int node = b * 256 + t;
    if (node <= N_NODES) row_ptr[node] = excl;
    cnt[t] = excl;
    __syncthreads();
#pragma unroll
    for (int j = 0; j < 18; j++) {
        if (ed[j] != 0xFFFFFFFFu) {
            int p = atomicAdd(&cnt[ed[j] & 255u], 1);
            col_src[p] = (int)(ed[j] >> 8);
        }
    }
}

// MFMA GEMM body. QUANT: biased-u8 hq (u=q+128) + alsc interleaved {al_s[h],scale}x4 + al_d.
template<bool AF32, bool QUANT>
__device__ __forceinline__ void gemm_body(int bid, int tid,
                                          const void* __restrict__ Ap,
                                          const u16* __restrict__ Bf,
                                          u16* __restrict__ C,
                                          char* __restrict__ hq,
                                          float* __restrict__ alsc,
                                          const float* __restrict__ a_src,
                                          const float* __restrict__ a_dst,
                                          float* __restrict__ al_d, int M) {
    int wave = tid >> 6, lane = tid & 63;
    int quad = lane >> 4, l15 = lane & 15;
    int row0 = bid * 64 + wave * 16;
    int m = row0 + l15;
    int mload = (m < M) ? m : (M - 1);

    short8 a[4];
    if (AF32) {
        const float* A = (const float*)Ap;
#pragma unroll
        for (int kk = 0; kk < 4; kk++) {
            const float* p = A + (size_t)mload * 128 + kk * 32 + quad * 8;
            float4 f0 = *(const float4*)p;
            float4 f1 = *(const float4*)(p + 4);
            short8 av;
            av[0] = (short)f2bf(f0.x); av[1] = (short)f2bf(f0.y);
            av[2] = (short)f2bf(f0.z); av[3] = (short)f2bf(f0.w);
            av[4] = (short)f2bf(f1.x); av[5] = (short)f2bf(f1.y);
            av[6] = (short)f2bf(f1.z); av[7] = (short)f2bf(f1.w);
            a[kk] = av;
        }
    } else {
        const u16* A = (const u16*)Ap;
#pragma unroll
        for (int kk = 0; kk < 4; kk++)
            a[kk] = *(const short8*)(A + (size_t)mload * 128 + kk * 32 + quad * 8);
    }

    float4v acc[8];
#pragma unroll
    for (int tn = 0; tn < 8; tn++) acc[tn] = (float4v){0.f, 0.f, 0.f, 0.f};

#pragma unroll
    for (int kk = 0; kk < 4; kk++) {
#pragma unroll
        for (int tn = 0; tn < 8; tn++) {
            short8 b = *(const short8*)(Bf + ((size_t)((kk * 8 + tn) * 64 + lane)) * 8);
            acc[tn] = __builtin_amdgcn_mfma_f32_16x16x32_bf16(a[kk], b, acc[tn], 0, 0, 0);
        }
    }

    float as0[4], as1[4], ad0[4], ad1[4];
    if (QUANT) {
#pragma unroll
        for (int hd = 0; hd < 4; hd++) {
            as0[hd] = a_src[hd * 32 + l15];
            as1[hd] = a_src[hd * 32 + 16 + l15];
            ad0[hd] = a_dst[hd * 32 + l15];
            ad1[hd] = a_dst[hd * 32 + 16 + l15];
        }
    }

#pragma unroll
    for (int rg = 0; rg < 4; rg++) {
        int gr = row0 + quad * 4 + rg;
        bool ok = (gr < M);
        if (!QUANT) {
            if (ok) {
#pragma unroll
                for (int tn = 0; tn < 8; tn++)
                    C[(size_t)gr * 128 + tn * 16 + l15] = f2bf(acc[tn][rg]);
            }
        } else {
            float amax = 0.f;
#pragma unroll
            for (int tn = 0; tn < 8; tn++) amax = fmaxf(amax, fabsf(acc[tn][rg]));
#pragma unroll
            for (int mm = 1; mm < 16; mm <<= 1) amax = fmaxf(amax, __shfl_xor(amax, mm, 64));
            float inv_s = (amax > 0.f) ? 127.f / amax : 0.f;
            if (ok) {
#pragma unroll
                for (int tn = 0; tn < 8; tn++) {
                    int q = (int)rintf(acc[tn][rg] * inv_s);
                    hq[(size_t)gr * 128 + tn * 16 + l15] = (char)(q + 128);   // biased u8
                }
            }
            float ps[4], pd[4];
#pragma unroll
            for (int hd = 0; hd < 4; hd++) {
                float c0 = acc[2 * hd][rg];
                float c1 = acc[2 * hd + 1][rg];
                ps[hd] = c0 * as0[hd] + c1 * as1[hd];
                pd[hd] = c0 * ad0[hd] + c1 * ad1[hd];
            }
#pragma unroll
            for (int mm = 1; mm < 16; mm <<= 1) {
#pragma unroll
                for (int hd = 0; hd < 4; hd++) {
                    ps[hd] += __shfl_xor(ps[hd], mm, 64);
                    pd[hd] += __shfl_xor(pd[hd], mm, 64);
                }
            }
            if (ok && l15 < 4) {
                float vs = (l15 == 0) ? ps[0] : (l15 == 1) ? ps[1] : (l15 == 2) ? ps[2] : ps[3];
                float vd = (l15 == 0) ? pd[0] : (l15 == 1) ? pd[1] : (l15 == 2) ? pd[2] : pd[3];
                alsc[(size_t)gr * 8 + l15 * 2]     = vs;                       // al_s[h]
                alsc[(size_t)gr * 8 + l15 * 2 + 1] = amax * (1.f / 127.f);     // scale (paired)
                al_d[gr * 4 + l15] = vd;
            }
        }
    }
}

// ---------------- merged kernel 1: prep (blocks 0..31) || bin (blocks 32..422) ------
__global__ __launch_bounds__(256) void k_prep_bin(const float* __restrict__ W1, const float* __restrict__ W2,
                                                  const float* __restrict__ WA, const float* __restrict__ WB,
                                                  u16* __restrict__ B1, u16* __restrict__ B2,
                                                  u16* __restrict__ BA, u16* __restrict__ BB,
                                                  const int* __restrict__ esrc, const int* __restrict__ edst,
                                                  int* bucket_cur, u32* __restrict__ binned) {
    if (blockIdx.x < 32)
        prep_body(blockIdx.x, threadIdx.x, W1, W2, WA, WB, B1, B2, BA, BB);
    else
        bin_body(blockIdx.x - 32, threadIdx.x, esrc, edst, bucket_cur, binned);
}

// ---------------- merged kernel 2: sort (blocks 0..390) || gemm1 (blocks 391..) ------
__global__ __launch_bounds__(256) void k_sort_gemm1(const u32* __restrict__ binned,
                                                    const int* __restrict__ bucket_cur,
                                                    int* __restrict__ row_ptr, int* __restrict__ col_src,
                                                    const float* __restrict__ embed, const u16* __restrict__ Bf1,
                                                    char* __restrict__ hq, float* __restrict__ alsc,
                                                    const float* __restrict__ a_src1, const float* __restrict__ a_dst1,
                                                    float* __restrict__ al_d) {
    if (blockIdx.x < NBUCK)
        sort_body(blockIdx.x, threadIdx.x, binned, bucket_cur, row_ptr, col_src);
    else
        gemm_body<true, true>(blockIdx.x - NBUCK, threadIdx.x, embed, Bf1, nullptr,
                              hq, alsc, a_src1, a_dst1, al_d, N_NODES);
}

// ---------------- standalone gemm (layer 2) ----------------
__global__ __launch_bounds__(256) void k_gemm2(const u16* __restrict__ Ap, const u16* __restrict__ Bf,
                                               char* __restrict__ hq, float* __restrict__ alsc,
                                               const float* __restrict__ a_src, const float* __restrict__ a_dst,
                                               float* __restrict__ al_d) {
    gemm_body<false, true>(blockIdx.x, threadIdx.x, Ap, Bf, nullptr, hq, alsc, a_src, a_dst, al_d, N_NODES);
}

// ---------------- fused aggregation: wide gather + perm/fma_mix decode (round-4 best) ----
template<bool XF32>
__global__ __launch_bounds__(256) void k_agg(const int* __restrict__ row_ptr, const int* __restrict__ col_src,
                      const float* __restrict__ alsc, const float* __restrict__ al_d,
                      const char* __restrict__ hq,
                      const void* __restrict__ xin, u16* __restrict__ xout) {
    int node = blockIdx.x * 4 + (threadIdx.x >> 6);
    int lane = threadIdx.x & 63;
    int l15 = lane & 15;
    int grp = lane >> 4;          // phase-B edge subgroup (0..3)
    int bh  = l15 >> 2;           // head of this lane's 8 dims
    int ae  = lane >> 2;          // phase-A edge slot (0..15)
    int ah  = lane & 3;           // phase-A head
    int beg = row_ptr[node], end = row_ptr[node + 1];
    int deg = end - beg;
    int degm1 = (deg > 0) ? deg - 1 : 0;
    float adst = al_d[node * 4 + ah];
    u32 loff = (u32)(l15 * 8);    // byte offset within a row

    float sw = 0.f, swl = 0.f;
    u32 h_one = 0x3C00u;          // f16 1.0
    float acc[8];
#pragma unroll
    for (int k = 0; k < 8; k++) acc[k] = 0.f;

    int nch = (deg + 15) >> 4;
    for (int cb = 0; cb < nch; cb++) {
        int c = cb * 16;
        int idx = c + l15;
        idx = (idx <= degm1) ? idx : degm1;          // clamp -> pad gathers reuse last line
        int sv = col_src[beg + idx];

        // ---- phase A: per-(slot,head) weight, one dwordx2
        int sA = __shfl(sv, ae, 64);
        float2 av = *(const float2*)(alsc + ((size_t)sA << 3) + (ah << 1));
        float ev = av.x + adst;
        ev = fmaxf(ev, 0.2f * ev);                   // leaky relu
        float w = __expf(ev);
        w = ((c + ae) < deg) ? w : 0.f;              // zero pad slots
        sw += w;
        float wsc = w * av.y;                        // fold src dequant scale

        // ---- phase B: 4 edges per iteration, dwordx2 gather + mix-precision MAC
#pragma unroll
        for (int i = 0; i < 4; i++) {
            int slot = 4 * i + grp;
            int s = __shfl(sv, slot, 64);
            float wl = __shfl(wsc, slot * 4 + bh, 64);
            u32 wlh;
            asm("v_cvt_f16_f32 %0, %1" : "=v"(wlh) : "v"(wl));
            FMIX_LO(swl, h_one, wlh);                // swl += f16(wl), f32 accum
            u32 off = ((u32)s << 7) + loff;
            uint2 hv = *(const uint2*)(hq + off);
            u32 p01 = __builtin_amdgcn_perm(0x64646464u, hv.x, 0x04010400u);
            u32 p23 = __builtin_amdgcn_perm(0x64646464u, hv.x, 0x04030402u);
            u32 p45 = __builtin_amdgcn_perm(0x64646464u, hv.y, 0x04010400u);
            u32 p67 = __builtin_amdgcn_perm(0x64646464u, hv.y, 0x04030402u);
            FMIX_LO(acc[0], p01, wlh); FMIX_HI(acc[1], p01, wlh);
            FMIX_LO(acc[2], p23, wlh); FMIX_HI(acc[3], p23, wlh);
            FMIX_LO(acc[4], p45, wlh); FMIX_HI(acc[5], p45, wlh);
            FMIX_LO(acc[6], p67, wlh); FMIX_HI(acc[7], p67, wlh);
        }
    }

    // remove the +1152 bias: acc_true = acc - 1152 * sum(wl)
#pragma unroll
    for (int k = 0; k < 8; k++) acc[k] = fmaf(swl, -1152.f, acc[k]);

    // sum(w): reduce over slot bits 2..5 (head preserved in bits 0..1)
#pragma unroll
    for (int mm = 4; mm < 64; mm <<= 1) sw += __shfl_xor(sw, mm, 64);
    float inv = 1.f / (__shfl(sw, bh, 64) + 1e-10f);

    // reduce accumulators across the 4 edge-subgroups (lane bits 4,5)
#pragma unroll
    for (int k = 0; k < 8; k++) {
        acc[k] += __shfl_xor(acc[k], 16, 64);
        acc[k] += __shfl_xor(acc[k], 32, 64);
    }

    if (grp == 0) {
        float r[8];
        if (XF32) {
            const float* x = (const float*)xin;
            float4 x0 = *(const float4*)&x[(size_t)node * 128 + l15 * 8];
            float4 x1 = *(const float4*)&x[(size_t)node * 128 + l15 * 8 + 4];
            r[0] = x0.x; r[1] = x0.y; r[2] = x0.z; r[3] = x0.w;
            r[4] = x1.x; r[5] = x1.y; r[6] = x1.z; r[7] = x1.w;
        } else {
            const u16* x = (const u16*)xin;
            short8 xv = *(const short8*)&x[(size_t)node * 128 + l15 * 8];
#pragma unroll
            for (int k = 0; k < 8; k++) r[k] = bf2f((u16)xv[k]);
        }
        u32 ow[4];
#pragma unroll
        for (int k = 0; k < 4; k++) {
            float a0 = acc[2 * k] * inv;
            float a1 = acc[2 * k + 1] * inv;
            a0 = (a0 > 0.f) ? a0 : (__expf(a0) - 1.f);
            a1 = (a1 > 0.f) ? a1 : (__expf(a1) - 1.f);
            ow[k] = (u32)f2bf(a0 + r[2 * k]) | ((u32)f2bf(a1 + r[2 * k + 1]) << 16);
        }
        *(uint4*)&xout[(size_t)node * 128 + l15 * 8] = make_uint4(ow[0], ow[1], ow[2], ow[3]);
    }
}

// ---------------- fused link predictor: gather-GEMM + relu + w2 dot ----------------
__global__ __launch_bounds__(256) void k_link(const int* __restrict__ psrc, const int* __restrict__ pdst,
                                              const u16* __restrict__ z,
                                              const u16* __restrict__ BfA, const u16* __restrict__ BfB,
                                              const float* __restrict__ b1, const float* __restrict__ w2,
                                              const float* __restrict__ b2, float* __restrict__ out) {
    int wave = threadIdx.x >> 6, lane = threadIdx.x & 63;
    int quad = lane >> 4, l15 = lane & 15;
    int row0 = blockIdx.x * 64 + wave * 16;
    int prow = row0 + l15;
    int pload = (prow < N_PAIRS) ? prow : (N_PAIRS - 1);
    int s = psrc[pload], d = pdst[pload];

    // gather A-fragments: per pair-row, 4 quads cooperatively cover the 256B z row
    short8 a1[4], a2[4];
#pragma unroll
    for (int kk = 0; kk < 4; kk++) {
        a1[kk] = *(const short8*)(z + (size_t)s * 128 + kk * 32 + quad * 8);
        a2[kk] = *(const short8*)(z + (size_t)d * 128 + kk * 32 + quad * 8);
    }

    float4v acc[8];
#pragma unroll
    for (int tn = 0; tn < 8; tn++) acc[tn] = (float4v){0.f, 0.f, 0.f, 0.f};

#pragma unroll
    for (int kk = 0; kk < 4; kk++) {
#pragma unroll
        for (int tn = 0; tn < 8; tn++) {
            short8 ba = *(const short8*)(BfA + ((size_t)((kk * 8 + tn) * 64 + lane)) * 8);
            acc[tn] = __builtin_amdgcn_mfma_f32_16x16x32_bf16(a1[kk], ba, acc[tn], 0, 0, 0);
            short8 bb = *(const short8*)(BfB + ((size_t)((kk * 8 + tn) * 64 + lane)) * 8);
            acc[tn] = __builtin_amdgcn_mfma_f32_16x16x32_bf16(a2[kk], bb, acc[tn], 0, 0, 0);
        }
    }

    float b1v[8], w2v[8];
#pragma unroll
    for (int tn = 0; tn < 8; tn++) {
        b1v[tn] = b1[tn * 16 + l15];
        w2v[tn] = w2[tn * 16 + l15];
    }
    float bb2 = b2[0];

#pragma unroll
    for (int rg = 0; rg < 4; rg++) {
        float part = 0.f;
#pragma unroll
        for (int tn = 0; tn < 8; tn++) {
            float h = acc[tn][rg] + b1v[tn];
            h = (h > 0.f) ? h : 0.f;
            part += h * w2v[tn];
        }
        // reduce over the 16 cols (lane bits 0..3, within quad)
#pragma unroll
        for (int mm = 1; mm < 16; mm <<= 1) part += __shfl_xor(part, mm, 64);
        int gr = row0 + quad * 4 + rg;
        if (l15 == 0 && gr < N_PAIRS) out[gr] = part + bb2;
    }
}

extern "C" void kernel_launch(void* const* d_in, const int* in_sizes, int n_in,
                              void* d_out, int out_size, void* d_ws, size_t ws_size,
                              hipStream_t stream) {
    const float* embed  = (const float*)d_in[0];
    const float* W1     = (const float*)d_in[1];
    const float* a_src1 = (const float*)d_in[2];
    const float* a_dst1 = (const float*)d_in[3];
    const float* W2     = (const float*)d_in[4];
    const float* a_src2 = (const float*)d_in[5];
    const float* a_dst2 = (const float*)d_in[6];
    const float* lp_w1  = (const float*)d_in[7];
    const float* lp_b1  = (const float*)d_in[8];
    const float* lp_w2  = (const float*)d_in[9];
    const float* lp_b2  = (const float*)d_in[10];
    const int*   edge   = (const int*)d_in[11];
    const int*   lsrc   = (const int*)d_in[12];
    const int*   ldst   = (const int*)d_in[13];
    float* out = (float*)d_out;

    char* ws = (char*)d_ws;
    size_t off = 0;
    auto alloc = [&](size_t bytes) -> char* {
        char* p = ws + off;
        off += (bytes + 255) & ~(size_t)255;
        return p;
    };
    int*  row_ptr    = (int*)alloc((N_NODES + 1) * 4);
    int*  bucket_cur = (int*)alloc(512 * 4);
    u32*  binned     = (u32*)alloc((size_t)NBUCK * BUCK_CAP * 4);
    int*  col_src    = (int*)alloc((size_t)N_EDGES * 4);
    char* hq         = (char*)alloc((size_t)N_NODES * 128);
    float* alsc      = (float*)alloc((size_t)N_NODES * 8 * 4);
    float* al_d      = (float*)alloc((size_t)N_NODES * 4 * 4);
    u16*  x1         = (u16*)alloc((size_t)N_NODES * 128 * 2);
    u16*  z          = (u16*)alloc((size_t)N_NODES * 128 * 2);
    u16*  Bf1        = (u16*)alloc(128 * 128 * 2);
    u16*  Bf2        = (u16*)alloc(128 * 128 * 2);
    u16*  BfA        = (u16*)alloc(128 * 128 * 2);
    u16*  BfB        = (u16*)alloc(128 * 128 * 2);

    const int* esrc = edge;
    const int* edst = edge + N_EDGES;
    const int GB = (N_NODES + 63) / 64;
    const int GP = (N_PAIRS + 63) / 64;

    // zero-based bucket cursors (removes bin's dependence on a cursor-init kernel)
    hipMemsetAsync(bucket_cur, 0, NBUCK * sizeof(int), stream);

    // kernel 1: weight pre-swizzle || edge binning (independent, merged)
    k_prep_bin<<<32 + BIN_GRID, 256, 0, stream>>>(W1, W2, lp_w1, lp_w1 + 128 * 128,
                                                  Bf1, Bf2, BfA, BfB,
                                                  esrc, edst, bucket_cur, binned);

    // kernel 2: counting sort || layer-1 GEMM (independent, merged; gemm fills the
    // machine while the 391 sort blocks run)
    k_sort_gemm1<<<NBUCK + GB, 256, 0, stream>>>(binned, bucket_cur, row_ptr, col_src,
                                                 embed, Bf1, hq, alsc, a_src1, a_dst1, al_d);

    k_agg<true><<<N_NODES / 4, 256, 0, stream>>>(row_ptr, col_src, alsc, al_d, hq, embed, x1);
    // layer 2
    k_gemm2<<<GB, 256, 0, stream>>>(x1, Bf2, hq, alsc, a_src2, a_dst2, al_d);
    k_agg<false><<<N_NODES / 4, 256, 0, stream>>>(row_ptr, col_src, alsc, al_d, hq, x1, z);
    // fused link predictor
    k_link<<<GP, 256, 0, stream>>>(lsrc, ldst, z, BfA, BfB, lp_b1, lp_w2, lp_b2, out);
}